// Round 12
// baseline (5595.257 us; speedup 1.0000x reference)
//
#include <hip/hip_runtime.h>
#include <hip/hip_bf16.h>

// T=512, B=64, D=1024, H=1024, 4H=4096
// Pass 0: pack Wi -> split-bf16 (hi/lo) in MFMA B-fragment order (ws, 16MB)
// Pass 1: G2 = x @ Wi + b via split-bf16 MFMA, scan-native layout:
//         G2[((step*256 + jg)*4 + gate)*256 + b*4 + u]  (bf16)
// Pass 2: cooperative scan. ROUND-12: 512 WGs (jg x batch-half), 256 thr,
//         4 waves = 2 row-tiles x 2 K-halves (split-K via 2 zS planes).
//         LDS 70.6KB -> 2 WGs/CU = 2 waves/SIMD: latency chains of the two
//         co-resident WGs interleave (round 9 had 1 wave/SIMD, zero hiding).
//         Schedule per step = round-9 verified: G2 prefetch at step start,
//         sc1 h reads, arrive + deferred out store + full poll.

typedef __attribute__((ext_vector_type(8))) short bf16x8;
typedef __attribute__((ext_vector_type(8))) unsigned short ushx8;
typedef __attribute__((ext_vector_type(4))) unsigned short ushx4;
typedef __attribute__((ext_vector_type(4))) float f32x4;
typedef __attribute__((ext_vector_type(2))) unsigned long long u64x2;

static __device__ __forceinline__ unsigned short f2bf(float x) {
    __hip_bfloat16 h = __float2bfloat16(x);
    return __builtin_bit_cast(unsigned short, h);
}
static __device__ __forceinline__ float bf2f(unsigned short u) {
    __hip_bfloat16 h = __builtin_bit_cast(__hip_bfloat16, u);
    return __bfloat162float(h);
}

// coherent (agent-scope, L2-bypassing) 16B load as 2 x u64 relaxed atomics
static __device__ __forceinline__ bf16x8 ld_h16(const unsigned long long* p) {
    unsigned long long a = __hip_atomic_load(p,     __ATOMIC_RELAXED, __HIP_MEMORY_SCOPE_AGENT);
    unsigned long long b = __hip_atomic_load(p + 1, __ATOMIC_RELAXED, __HIP_MEMORY_SCOPE_AGENT);
    u64x2 v; v.x = a; v.y = b;
    return __builtin_bit_cast(bf16x8, v);
}

static __device__ __forceinline__ void gl_lds16(const void* g, void* l) {
    __builtin_amdgcn_global_load_lds(
        (const __attribute__((address_space(1))) unsigned int*)g,
        (__attribute__((address_space(3))) unsigned int*)l, 16, 0, 0);
}

static __device__ __forceinline__ float sigm_fast(float x) {
    return 1.f / (1.f + __expf(-x));
}
static __device__ __forceinline__ float tanh_fast(float x) {
    float e = __expf(2.f * x);
    return 1.f - 2.f / (e + 1.f);
}

// ---------------------------------------------------------------------------
// Pass 0: pack Wi[1024][4096] f32 -> WiHi/WiLo bf16 in B-fragment order.
// ---------------------------------------------------------------------------
__global__ __launch_bounds__(256)
void wi_pack(const float* __restrict__ Wi, unsigned short* __restrict__ WiHi,
             unsigned short* __restrict__ WiLo)
{
    const int bid = blockIdx.x;            // 1024 = tn(32) x kb(32)
    const int tn = bid >> 5, kb = bid & 31;
    const int t = threadIdx.x;
    const int c = t & 127, ko = t >> 7;
    const float* src = Wi + (size_t)(kb * 32 + ko * 16) * 4096 + tn * 128 + c;
    const size_t dbase = ((size_t)(tn * 32 + kb)) * 4096 + c * 8;
#pragma unroll
    for (int o = 0; o < 2; ++o) {
        ushx8 hv, lv;
#pragma unroll
        for (int q = 0; q < 8; ++q) {
            float v = src[(size_t)(o * 8 + q) * 4096];
            unsigned short h = f2bf(v);
            hv[q] = h; lv[q] = f2bf(v - bf2f(h));
        }
        int kq = ko * 2 + o;
        *(ushx8*)(WiHi + dbase + kq * 1024) = hv;
        *(ushx8*)(WiLo + dbase + kq * 1024) = lv;
    }
}

// ---------------------------------------------------------------------------
// Pass 1: G2 = x @ Wi + bias, split-bf16 MFMA, 128x128 tile, BK=32, 4 waves.
// ---------------------------------------------------------------------------
__global__ __launch_bounds__(256)
void xwi_gemm_mfma(const float* __restrict__ x,
                   const unsigned short* __restrict__ WiHi,
                   const unsigned short* __restrict__ WiLo,
                   const float* __restrict__ bias,
                   unsigned short* __restrict__ G2)
{
    __shared__ __align__(16) unsigned short AHi[4096], ALo[4096];
    __shared__ __align__(16) unsigned short BHi[4096], BLo[4096];
    const int bid = blockIdx.x;
    const int bm = bid >> 5, bn = bid & 31;
    const int m0 = bm << 7, n0 = bn << 7;
    const int t = threadIdx.x;
    const int w = t >> 6, l = t & 63, lq = l >> 4, lc = l & 15;
    const int wm = w >> 1, wn = w & 1;

    f32x4 acc[4][4] = {};
    const int row = t >> 1, kh = t & 1;
    const float* xrow = x + (size_t)(m0 + row) * 1024 + kh * 16;
    const unsigned short* bHsl = WiHi + (size_t)(bn * 32) * 4096;
    const unsigned short* bLsl = WiLo + (size_t)(bn * 32) * 4096;

    for (int kb = 0; kb < 32; ++kb) {
        float4 f0 = *(const float4*)(xrow + kb * 32 + 0);
        float4 f1 = *(const float4*)(xrow + kb * 32 + 4);
        float4 f2 = *(const float4*)(xrow + kb * 32 + 8);
        float4 f3 = *(const float4*)(xrow + kb * 32 + 12);
        float fs[16] = {f0.x, f0.y, f0.z, f0.w, f1.x, f1.y, f1.z, f1.w,
                        f2.x, f2.y, f2.z, f2.w, f3.x, f3.y, f3.z, f3.w};
#pragma unroll
        for (int o = 0; o < 2; ++o) {
            ushx8 hv, lv;
#pragma unroll
            for (int q = 0; q < 8; ++q) {
                float v = fs[o * 8 + q];
                unsigned short h = f2bf(v);
                hv[q] = h; lv[q] = f2bf(v - bf2f(h));
            }
            int kq = kh * 2 + o;
            *(ushx8*)&AHi[kq * 1024 + row * 8] = hv;
            *(ushx8*)&ALo[kq * 1024 + row * 8] = lv;
        }
        {
            const unsigned short* sH = bHsl + (size_t)kb * 4096;
            const unsigned short* sL = bLsl + (size_t)kb * 4096;
            gl_lds16(sH + (size_t)(w * 128 + l) * 8,      &BHi[(w * 128) * 8]);
            gl_lds16(sH + (size_t)(w * 128 + 64 + l) * 8, &BHi[(w * 128 + 64) * 8]);
            gl_lds16(sL + (size_t)(w * 128 + l) * 8,      &BLo[(w * 128) * 8]);
            gl_lds16(sL + (size_t)(w * 128 + 64 + l) * 8, &BLo[(w * 128 + 64) * 8]);
        }
        __syncthreads();

        bf16x8 xh[4], xl[4], wh_[4], wl_[4];
#pragma unroll
        for (int a = 0; a < 4; ++a) {
            int off = lq * 1024 + (wm * 64 + a * 16 + lc) * 8;
            xh[a] = *(const bf16x8*)&AHi[off];
            xl[a] = *(const bf16x8*)&ALo[off];
        }
#pragma unroll
        for (int b = 0; b < 4; ++b) {
            int off = lq * 1024 + (wn * 64 + b * 16 + lc) * 8;
            wh_[b] = *(const bf16x8*)&BHi[off];
            wl_[b] = *(const bf16x8*)&BLo[off];
        }
#pragma unroll
        for (int a = 0; a < 4; ++a)
#pragma unroll
            for (int b = 0; b < 4; ++b) {
                acc[a][b] = __builtin_amdgcn_mfma_f32_16x16x32_bf16(wh_[b], xh[a], acc[a][b], 0, 0, 0);
                acc[a][b] = __builtin_amdgcn_mfma_f32_16x16x32_bf16(wl_[b], xh[a], acc[a][b], 0, 0, 0);
                acc[a][b] = __builtin_amdgcn_mfma_f32_16x16x32_bf16(wh_[b], xl[a], acc[a][b], 0, 0, 0);
            }
        __syncthreads();
    }

    float bv[4][4];
#pragma unroll
    for (int b = 0; b < 4; ++b)
#pragma unroll
        for (int r = 0; r < 4; ++r)
            bv[b][r] = bias[n0 + wn * 64 + b * 16 + lq * 4 + r];
#pragma unroll
    for (int a = 0; a < 4; ++a) {
        int m = m0 + wm * 64 + a * 16 + lc;
        int step = m >> 6, b_el = m & 63;
#pragma unroll
        for (int b = 0; b < 4; ++b) {
            int j_abs = n0 + wn * 64 + b * 16 + lq * 4;
            int gate = j_abs >> 10;
            int wg_t = (j_abs & 1023) >> 2;
            ushx4 sv;
#pragma unroll
            for (int r = 0; r < 4; ++r) sv[r] = f2bf(acc[a][b][r] + bv[b][r]);
            *(ushx4*)(G2 + (((size_t)(step * 256 + wg_t) * 4 + gate) * 256 + b_el * 4)) = sv;
        }
    }
}

// ---------------------------------------------------------------------------
// Pass 2: cooperative MFMA scan. 512 WGs x 256 threads, 2 WGs/CU.
// WG (jg = wgid>>1, bh = wgid&1) owns batch rows bh*32..+31, units jg*4..+3.
// Wave w: row-tile rt=w&1 (16 rows), K-half kh=w>>1 (512 k). Split-K partials
// land in zS[kh]; summed in f32 elementwise (t<128).
// ---------------------------------------------------------------------------
__global__ __launch_bounds__(256, 2)
void lstm_scan_mfma(const unsigned short* __restrict__ G2,
                    const float* __restrict__ Wh,
                    const float* __restrict__ h0, const float* __restrict__ c0,
                    float* __restrict__ out,
                    unsigned int* __restrict__ hp0,
                    unsigned int* __restrict__ hp1,
                    unsigned int* __restrict__ flags)
{
    __shared__ __align__(16) unsigned short WhHiS[16384];  // 32 KB
    __shared__ __align__(16) unsigned short WhLoS[16384];  // 32 KB
    __shared__ float zS[2][32 * 20];                       // 5 KB

    const int t    = threadIdx.x;
    const int wgid = blockIdx.x;         // 0..511
    const int jg   = wgid >> 1;
    const int bh   = wgid & 1;
    const int w  = t >> 6, l = t & 63, lq = l >> 4, lc = l & 15;
    const int rt = w & 1, kh = w >> 1;

    // Wh slice -> LDS (once): 16 z-cols of jg, hi/lo split, B-fragment order
    for (int idx = t; idx < 16384; idx += 256) {
        int k = idx >> 4, c = idx & 15;
        int gcol = (c >> 2) * 1024 + jg * 4 + (c & 3);
        float wv = Wh[(size_t)k * 4096 + gcol];
        unsigned short hi = f2bf(wv);
        unsigned short lo = f2bf(wv - bf2f(hi));
        int pos = (((k >> 5) * 64) + (((k >> 3) & 3) * 16 + c)) * 8 + (k & 7);
        WhHiS[pos] = hi; WhLoS[pos] = lo;
    }

    // init hp0 from h0 (bf16 hi only, sc1 -> IF$): 64 pairs per WG
    if (t < 64) {
        int idx = wgid * 64 + t;
        int b = idx >> 9, k = (idx & 511) * 2;
        unsigned short h0s = f2bf(h0[b * 1024 + k]);
        unsigned short h1s = f2bf(h0[b * 1024 + k + 1]);
        int p32 = ((k >> 3) * 64 + b) * 4 + ((k & 7) >> 1);
        __hip_atomic_store(hp0 + p32, (unsigned int)h0s | ((unsigned int)h1s << 16),
                           __ATOMIC_RELAXED, __HIP_MEMORY_SCOPE_AGENT);
    }

    const int tl = t & 127;
    const int b_el = bh * 32 + (tl >> 2);   // valid use only when t<128
    const int u_el = tl & 3;
    const int j = jg * 4 + u_el;
    float c_state = 0.f;
    if (t < 128) c_state = c0[b_el * 1024 + j];

    // initial barrier (spread flags, each thread polls 2)
    {
        asm volatile("s_waitcnt vmcnt(0)" ::: "memory");
        __syncthreads();
        if (t == 0)
            __hip_atomic_store(&flags[wgid * 32], 1u, __ATOMIC_RELAXED,
                               __HIP_MEMORY_SCOPE_AGENT);
        for (;;) {
            unsigned int f0 = __hip_atomic_load(&flags[t * 32], __ATOMIC_RELAXED,
                                                __HIP_MEMORY_SCOPE_AGENT);
            unsigned int f1 = __hip_atomic_load(&flags[(t + 256) * 32], __ATOMIC_RELAXED,
                                                __HIP_MEMORY_SCOPE_AGENT);
            if (f0 >= 1u && f1 >= 1u) break;
        }
        __syncthreads();
        asm volatile("" ::: "memory");
    }

    const int arow = bh * 32 + rt * 16 + lc;
    for (int step = 0; step < 512; ++step) {
        const unsigned long long* hH =
            (const unsigned long long*)((step & 1) ? hp1 : hp0);
        unsigned int* nH = (step & 1) ? hp0 : hp1;

        // G2 prefetch (current step, t<128): latency hides under K loop
        unsigned short gvi = 0, gvf = 0, gvg = 0, gvo = 0;
        if (t < 128) {
            size_t pb = ((size_t)(step * 256 + jg) * 4) * 256 + bh * 128 + tl;
            gvi = G2[pb];
            gvf = G2[pb + 256];
            gvg = G2[pb + 512];
            gvo = G2[pb + 768];
        }

        f32x4 acc0 = {0.f, 0.f, 0.f, 0.f};
        f32x4 acc2 = {0.f, 0.f, 0.f, 0.f};

        // K-half loop: 16 kb, software-pipelined in 2 groups of 8
        bf16x8 ahA[8], ahB[8];
#pragma unroll
        for (int i = 0; i < 8; ++i) {
            int kb = kh * 16 + i;
            int a64 = ((kb * 4 + lq) * 64 + arow) * 2;
            ahA[i] = ld_h16(hH + a64);
        }
#pragma unroll
        for (int i = 0; i < 8; ++i) {
            int kb = kh * 16 + 8 + i;
            int a64 = ((kb * 4 + lq) * 64 + arow) * 2;
            ahB[i] = ld_h16(hH + a64);
        }
#pragma unroll
        for (int i = 0; i < 8; ++i) {
            int kb = kh * 16 + i;
            int bpos = (kb * 64 + l) * 8;
            bf16x8 bhv = *(const bf16x8*)&WhHiS[bpos];
            bf16x8 blv = *(const bf16x8*)&WhLoS[bpos];
            acc0 = __builtin_amdgcn_mfma_f32_16x16x32_bf16(ahA[i], bhv, acc0, 0, 0, 0);
            acc2 = __builtin_amdgcn_mfma_f32_16x16x32_bf16(ahA[i], blv, acc2, 0, 0, 0);
        }
#pragma unroll
        for (int i = 0; i < 8; ++i) {
            int kb = kh * 16 + 8 + i;
            int bpos = (kb * 64 + l) * 8;
            bf16x8 bhv = *(const bf16x8*)&WhHiS[bpos];
            bf16x8 blv = *(const bf16x8*)&WhLoS[bpos];
            acc0 = __builtin_amdgcn_mfma_f32_16x16x32_bf16(ahB[i], bhv, acc0, 0, 0, 0);
            acc2 = __builtin_amdgcn_mfma_f32_16x16x32_bf16(ahB[i], blv, acc2, 0, 0, 0);
        }

        // split-K partial -> zS[kh] (rows 0..31 local, stride 20)
#pragma unroll
        for (int r = 0; r < 4; ++r)
            zS[kh][(rt * 16 + lq * 4 + r) * 20 + lc] = acc0[r] + acc2[r];
        __syncthreads();

        float nh = 0.f;
        if (t < 128) {
            const float* z0 = &zS[0][(tl >> 2) * 20];
            const float* z1 = &zS[1][(tl >> 2) * 20];
            float zi = bf2f(gvi) + z0[u_el]      + z1[u_el];
            float zf = bf2f(gvf) + z0[4 + u_el]  + z1[4 + u_el];
            float zg = bf2f(gvg) + z0[8 + u_el]  + z1[8 + u_el];
            float zo = bf2f(gvo) + z0[12 + u_el] + z1[12 + u_el];

            float ig = sigm_fast(zi);
            float fg = sigm_fast(zf);
            float gg = tanh_fast(zg);
            float og = sigm_fast(zo);

            c_state = fg * c_state + ig * gg;
            nh = og * tanh_fast(c_state);
        }

        if (step == 511) {
            if (t < 128) out[(size_t)step * 65536 + b_el * 1024 + j] = nh;
            break;                      // no publish/barrier needed
        }

        // publish h (bf16 hi only, sc1 -> IF$, packed pairs via shfl)
        if (t < 128) {
            unsigned int hiw = f2bf(nh);
            unsigned int hi_o = (unsigned int)__shfl_xor((int)hiw, 1);
            if ((t & 1) == 0) {
                int p32 = ((j >> 3) * 64 + b_el) * 4 + ((j & 7) >> 1);
                __hip_atomic_store(nH + p32, (hiw & 0xffffu) | (hi_o << 16),
                                   __ATOMIC_RELAXED, __HIP_MEMORY_SCOPE_AGENT);
            }
        }

        // barrier: arrive (publishes drained), deferred out store, poll
        asm volatile("s_waitcnt vmcnt(0)" ::: "memory");
        __syncthreads();
        unsigned int target = (unsigned int)(step + 2);
        if (t == 0)
            __hip_atomic_store(&flags[wgid * 32], target, __ATOMIC_RELAXED,
                               __HIP_MEMORY_SCOPE_AGENT);
        if (t < 128)
            out[(size_t)step * 65536 + b_el * 1024 + j] = nh;  // drains next step
        for (;;) {
            unsigned int f0 = __hip_atomic_load(&flags[t * 32], __ATOMIC_RELAXED,
                                                __HIP_MEMORY_SCOPE_AGENT);
            unsigned int f1 = __hip_atomic_load(&flags[(t + 256) * 32], __ATOMIC_RELAXED,
                                                __HIP_MEMORY_SCOPE_AGENT);
            if (f0 >= target && f1 >= target) break;
        }
        __syncthreads();
        asm volatile("" ::: "memory");
    }
}

// ---------------------------------------------------------------------------
extern "C" void kernel_launch(void* const* d_in, const int* in_sizes, int n_in,
                              void* d_out, int out_size, void* d_ws, size_t ws_size,
                              hipStream_t stream)
{
    const float* x  = (const float*)d_in[0];
    const float* h0 = (const float*)d_in[1];
    const float* c0 = (const float*)d_in[2];
    const float* Wi = (const float*)d_in[3];
    const float* Wh = (const float*)d_in[4];
    const float* bb = (const float*)d_in[5];
    float* out = (float*)d_out;

    // ws layout: hp0/hp1 (128KB each) | flags 64KB | WiHi 8MB | WiLo 8MB | G2 268MB
    unsigned int* hp0 = (unsigned int*)d_ws;
    unsigned int* hp1 = hp0 + 32768;
    unsigned int* flags = hp1 + 32768;          // 512 * 32 u32 = 64KB
    unsigned short* WiHi = (unsigned short*)(flags + 16384);
    unsigned short* WiLo = WiHi + 4194304;
    unsigned short* G2 = WiLo + 4194304;

    hipMemsetAsync(flags, 0, 16384 * sizeof(unsigned int), stream);
    wi_pack<<<dim3(1024), dim3(256), 0, stream>>>(Wi, WiHi, WiLo);
    xwi_gemm_mfma<<<dim3(8192), dim3(256), 0, stream>>>(x, WiHi, WiLo, bb, G2);

    void* args[] = {(void*)&G2, (void*)&Wh, (void*)&h0, (void*)&c0, (void*)&out,
                    (void*)&hp0, (void*)&hp1, (void*)&flags};
    hipLaunchCooperativeKernel(reinterpret_cast<void*>(&lstm_scan_mfma),
                               dim3(512), dim3(256), args, 0, stream);
}

// Round 13
// 3164.471 us; speedup vs baseline: 1.7681x; 1.7681x over previous
//
#include <hip/hip_runtime.h>
#include <hip/hip_bf16.h>

// T=512, B=64, D=1024, H=1024, 4H=4096
// Pass 0: pack Wi -> split-bf16 (hi/lo) in MFMA B-fragment order (ws, 16MB)
// Pass 1: G2 = x @ Wi + b via split-bf16 MFMA, scan-native layout:
//         G2[((step*128 + jg)*2 + bh)*1024 + gate*256 + b_l*8 + u]  (bf16)
// Pass 2: cooperative scan, 256 WGs (jg x batch-half), ROUND-13 tile:
//         32 rows x 32 cols per WG (was 64x16). Wave (rt,kh) reads a
//         DISTINCT 16-row x K-half h block -> sc1 broadcast 32 -> 16 MB/step
//         (sc1 never dedupes; fewer loads is the only lever). Split-K summed
//         via 2 zS planes. Barrier/schedule = round-9 verified.

typedef __attribute__((ext_vector_type(8))) short bf16x8;
typedef __attribute__((ext_vector_type(8))) unsigned short ushx8;
typedef __attribute__((ext_vector_type(4))) unsigned short ushx4;
typedef __attribute__((ext_vector_type(4))) float f32x4;
typedef __attribute__((ext_vector_type(2))) unsigned long long u64x2;

static __device__ __forceinline__ unsigned short f2bf(float x) {
    __hip_bfloat16 h = __float2bfloat16(x);
    return __builtin_bit_cast(unsigned short, h);
}
static __device__ __forceinline__ float bf2f(unsigned short u) {
    __hip_bfloat16 h = __builtin_bit_cast(__hip_bfloat16, u);
    return __bfloat162float(h);
}

// coherent (agent-scope, L2-bypassing) 16B load as 2 x u64 relaxed atomics
static __device__ __forceinline__ bf16x8 ld_h16(const unsigned long long* p) {
    unsigned long long a = __hip_atomic_load(p,     __ATOMIC_RELAXED, __HIP_MEMORY_SCOPE_AGENT);
    unsigned long long b = __hip_atomic_load(p + 1, __ATOMIC_RELAXED, __HIP_MEMORY_SCOPE_AGENT);
    u64x2 v; v.x = a; v.y = b;
    return __builtin_bit_cast(bf16x8, v);
}

static __device__ __forceinline__ void gl_lds16(const void* g, void* l) {
    __builtin_amdgcn_global_load_lds(
        (const __attribute__((address_space(1))) unsigned int*)g,
        (__attribute__((address_space(3))) unsigned int*)l, 16, 0, 0);
}

static __device__ __forceinline__ float sigm_fast(float x) {
    return 1.f / (1.f + __expf(-x));
}
static __device__ __forceinline__ float tanh_fast(float x) {
    float e = __expf(2.f * x);
    return 1.f - 2.f / (e + 1.f);
}

// ---------------------------------------------------------------------------
// Pass 0: pack Wi[1024][4096] f32 -> WiHi/WiLo bf16 in B-fragment order.
// ---------------------------------------------------------------------------
__global__ __launch_bounds__(256)
void wi_pack(const float* __restrict__ Wi, unsigned short* __restrict__ WiHi,
             unsigned short* __restrict__ WiLo)
{
    const int bid = blockIdx.x;            // 1024 = tn(32) x kb(32)
    const int tn = bid >> 5, kb = bid & 31;
    const int t = threadIdx.x;
    const int c = t & 127, ko = t >> 7;
    const float* src = Wi + (size_t)(kb * 32 + ko * 16) * 4096 + tn * 128 + c;
    const size_t dbase = ((size_t)(tn * 32 + kb)) * 4096 + c * 8;
#pragma unroll
    for (int o = 0; o < 2; ++o) {
        ushx8 hv, lv;
#pragma unroll
        for (int q = 0; q < 8; ++q) {
            float v = src[(size_t)(o * 8 + q) * 4096];
            unsigned short h = f2bf(v);
            hv[q] = h; lv[q] = f2bf(v - bf2f(h));
        }
        int kq = ko * 2 + o;
        *(ushx8*)(WiHi + dbase + kq * 1024) = hv;
        *(ushx8*)(WiLo + dbase + kq * 1024) = lv;
    }
}

// ---------------------------------------------------------------------------
// Pass 1: G2 = x @ Wi + bias, split-bf16 MFMA, 128x128 tile, BK=32, 4 waves.
// Epilogue writes the round-13 scan-native layout.
// ---------------------------------------------------------------------------
__global__ __launch_bounds__(256)
void xwi_gemm_mfma(const float* __restrict__ x,
                   const unsigned short* __restrict__ WiHi,
                   const unsigned short* __restrict__ WiLo,
                   const float* __restrict__ bias,
                   unsigned short* __restrict__ G2)
{
    __shared__ __align__(16) unsigned short AHi[4096], ALo[4096];
    __shared__ __align__(16) unsigned short BHi[4096], BLo[4096];
    const int bid = blockIdx.x;
    const int bm = bid >> 5, bn = bid & 31;
    const int m0 = bm << 7, n0 = bn << 7;
    const int t = threadIdx.x;
    const int w = t >> 6, l = t & 63, lq = l >> 4, lc = l & 15;
    const int wm = w >> 1, wn = w & 1;

    f32x4 acc[4][4] = {};
    const int row = t >> 1, kh = t & 1;
    const float* xrow = x + (size_t)(m0 + row) * 1024 + kh * 16;
    const unsigned short* bHsl = WiHi + (size_t)(bn * 32) * 4096;
    const unsigned short* bLsl = WiLo + (size_t)(bn * 32) * 4096;

    for (int kb = 0; kb < 32; ++kb) {
        float4 f0 = *(const float4*)(xrow + kb * 32 + 0);
        float4 f1 = *(const float4*)(xrow + kb * 32 + 4);
        float4 f2 = *(const float4*)(xrow + kb * 32 + 8);
        float4 f3 = *(const float4*)(xrow + kb * 32 + 12);
        float fs[16] = {f0.x, f0.y, f0.z, f0.w, f1.x, f1.y, f1.z, f1.w,
                        f2.x, f2.y, f2.z, f2.w, f3.x, f3.y, f3.z, f3.w};
#pragma unroll
        for (int o = 0; o < 2; ++o) {
            ushx8 hv, lv;
#pragma unroll
            for (int q = 0; q < 8; ++q) {
                float v = fs[o * 8 + q];
                unsigned short h = f2bf(v);
                hv[q] = h; lv[q] = f2bf(v - bf2f(h));
            }
            int kq = kh * 2 + o;
            *(ushx8*)&AHi[kq * 1024 + row * 8] = hv;
            *(ushx8*)&ALo[kq * 1024 + row * 8] = lv;
        }
        {
            const unsigned short* sH = bHsl + (size_t)kb * 4096;
            const unsigned short* sL = bLsl + (size_t)kb * 4096;
            gl_lds16(sH + (size_t)(w * 128 + l) * 8,      &BHi[(w * 128) * 8]);
            gl_lds16(sH + (size_t)(w * 128 + 64 + l) * 8, &BHi[(w * 128 + 64) * 8]);
            gl_lds16(sL + (size_t)(w * 128 + l) * 8,      &BLo[(w * 128) * 8]);
            gl_lds16(sL + (size_t)(w * 128 + 64 + l) * 8, &BLo[(w * 128 + 64) * 8]);
        }
        __syncthreads();

        bf16x8 xh[4], xl[4], wh_[4], wl_[4];
#pragma unroll
        for (int a = 0; a < 4; ++a) {
            int off = lq * 1024 + (wm * 64 + a * 16 + lc) * 8;
            xh[a] = *(const bf16x8*)&AHi[off];
            xl[a] = *(const bf16x8*)&ALo[off];
        }
#pragma unroll
        for (int b = 0; b < 4; ++b) {
            int off = lq * 1024 + (wn * 64 + b * 16 + lc) * 8;
            wh_[b] = *(const bf16x8*)&BHi[off];
            wl_[b] = *(const bf16x8*)&BLo[off];
        }
#pragma unroll
        for (int a = 0; a < 4; ++a)
#pragma unroll
            for (int b = 0; b < 4; ++b) {
                acc[a][b] = __builtin_amdgcn_mfma_f32_16x16x32_bf16(wh_[b], xh[a], acc[a][b], 0, 0, 0);
                acc[a][b] = __builtin_amdgcn_mfma_f32_16x16x32_bf16(wl_[b], xh[a], acc[a][b], 0, 0, 0);
                acc[a][b] = __builtin_amdgcn_mfma_f32_16x16x32_bf16(wh_[b], xl[a], acc[a][b], 0, 0, 0);
            }
        __syncthreads();
    }

    float bv[4][4];
#pragma unroll
    for (int b = 0; b < 4; ++b)
#pragma unroll
        for (int r = 0; r < 4; ++r)
            bv[b][r] = bias[n0 + wn * 64 + b * 16 + lq * 4 + r];
#pragma unroll
    for (int a = 0; a < 4; ++a) {
        int m = m0 + wm * 64 + a * 16 + lc;
        int step = m >> 6, b_abs = m & 63;
        int bh_ = b_abs >> 5, b_l = b_abs & 31;
#pragma unroll
        for (int b = 0; b < 4; ++b) {
            int j_abs = n0 + wn * 64 + b * 16 + lq * 4;
            int gate = j_abs >> 10;
            int hid  = j_abs & 1023;
            int jg_t = hid >> 3, u0 = hid & 7;   // u0 in {0,4}
            ushx4 sv;
#pragma unroll
            for (int r = 0; r < 4; ++r) sv[r] = f2bf(acc[a][b][r] + bv[b][r]);
            size_t addr = (((size_t)(step * 128 + jg_t) * 2 + bh_) * 1024)
                          + gate * 256 + b_l * 8 + u0;
            *(ushx4*)(G2 + addr) = sv;
        }
    }
}

// ---------------------------------------------------------------------------
// Pass 2: cooperative MFMA scan. 256 WGs x 256 threads (4 waves), 1 WG/CU.
// WG (jg = wgid>>1, bh = wgid&1): batch rows bh*32..+31, units jg*8..+7
// (32 z-cols). Wave w: row-tile rt=w&1 (16 rows), K-half kh=w>>1 — each wave
// reads a DISTINCT h block (halves sc1 broadcast). Split-K via zS[2].
// ---------------------------------------------------------------------------
__global__ __launch_bounds__(256, 1)
void lstm_scan_mfma(const unsigned short* __restrict__ G2,
                    const float* __restrict__ Wh,
                    const float* __restrict__ h0, const float* __restrict__ c0,
                    float* __restrict__ out,
                    unsigned int* __restrict__ hp0,
                    unsigned int* __restrict__ hp1,
                    unsigned int* __restrict__ flags)
{
    __shared__ __align__(16) unsigned short WhHiS[32768];  // 64 KB, [ct][frag]
    __shared__ __align__(16) unsigned short WhLoS[32768];  // 64 KB
    __shared__ float zS[2 * 32 * 36];                      // 9.2 KB

    const int t    = threadIdx.x;
    const int wgid = blockIdx.x;         // 0..255
    const int jg   = wgid >> 1;
    const int bh   = wgid & 1;
    const int w  = t >> 6, l = t & 63, lq = l >> 4, lc = l & 15;
    const int rt = w & 1, kh = w >> 1;

    // Wh slice -> LDS (once): 32 z-cols (c5 = gate*8+u), hi/lo, B-frag order
    for (int idx = t; idx < 32768; idx += 256) {
        int k = idx >> 5, c5 = idx & 31;
        int gcol = (c5 >> 3) * 1024 + jg * 8 + (c5 & 7);
        float wv = Wh[(size_t)k * 4096 + gcol];
        unsigned short hi = f2bf(wv);
        unsigned short lo = f2bf(wv - bf2f(hi));
        int ct = c5 >> 4, c = c5 & 15;
        int pos = ct * 16384 + (((k >> 5) * 64) + (((k >> 3) & 3) * 16 + c)) * 8 + (k & 7);
        WhHiS[pos] = hi; WhLoS[pos] = lo;
    }

    // init hp0 from h0 (bf16 hi only, sc1 -> IF$): 128 pairs per WG
    if (t < 128) {
        int idx = wgid * 128 + t;
        int b = idx >> 9, k = (idx & 511) * 2;
        unsigned short h0s = f2bf(h0[b * 1024 + k]);
        unsigned short h1s = f2bf(h0[b * 1024 + k + 1]);
        int p32 = ((k >> 3) * 64 + b) * 4 + ((k & 7) >> 1);
        __hip_atomic_store(hp0 + p32, (unsigned int)h0s | ((unsigned int)h1s << 16),
                           __ATOMIC_RELAXED, __HIP_MEMORY_SCOPE_AGENT);
    }

    const int b_l = t >> 3, u_el = t & 7;
    const int b_el = bh * 32 + b_l;
    const int j = jg * 8 + u_el;
    float c_state = c0[b_el * 1024 + j];

    // initial barrier (round-5/9 form: spread flags, all-thread poll)
    {
        asm volatile("s_waitcnt vmcnt(0)" ::: "memory");
        __syncthreads();
        if (t == 0)
            __hip_atomic_store(&flags[wgid * 32], 1u, __ATOMIC_RELAXED,
                               __HIP_MEMORY_SCOPE_AGENT);
        while (__hip_atomic_load(&flags[t * 32], __ATOMIC_RELAXED,
                                 __HIP_MEMORY_SCOPE_AGENT) < 1u) {}
        __syncthreads();
        asm volatile("" ::: "memory");
    }

    const int arow = bh * 32 + rt * 16 + lc;
    for (int step = 0; step < 512; ++step) {
        const unsigned long long* hH =
            (const unsigned long long*)((step & 1) ? hp1 : hp0);
        unsigned int* nH = (step & 1) ? hp0 : hp1;

        // G2 prefetch: contiguous 2KB/WG panel, 4 x 2B per thread (dense)
        size_t pb = (((size_t)(step * 128 + jg) * 2 + bh) * 1024) + t;
        unsigned short gvi = G2[pb];
        unsigned short gvf = G2[pb + 256];
        unsigned short gvg = G2[pb + 512];
        unsigned short gvo = G2[pb + 768];

        // K-half loop: 16 kb, distinct rows+K-half per wave
        bf16x8 ah[16];
#pragma unroll
        for (int i = 0; i < 16; ++i) {
            int kb = kh * 16 + i;
            int a64 = ((kb * 4 + lq) * 64 + arow) * 2;
            ah[i] = ld_h16(hH + a64);
        }

        f32x4 acc00 = {0.f,0.f,0.f,0.f}, acc01 = {0.f,0.f,0.f,0.f};
        f32x4 acc10 = {0.f,0.f,0.f,0.f}, acc11 = {0.f,0.f,0.f,0.f};
#pragma unroll
        for (int i = 0; i < 16; ++i) {
            int kb = kh * 16 + i;
            int b0 = (kb * 64 + l) * 8;
            bf16x8 bh0 = *(const bf16x8*)&WhHiS[b0];
            bf16x8 bl0 = *(const bf16x8*)&WhLoS[b0];
            acc00 = __builtin_amdgcn_mfma_f32_16x16x32_bf16(ah[i], bh0, acc00, 0, 0, 0);
            acc01 = __builtin_amdgcn_mfma_f32_16x16x32_bf16(ah[i], bl0, acc01, 0, 0, 0);
            bf16x8 bh1 = *(const bf16x8*)&WhHiS[16384 + b0];
            bf16x8 bl1 = *(const bf16x8*)&WhLoS[16384 + b0];
            acc10 = __builtin_amdgcn_mfma_f32_16x16x32_bf16(ah[i], bh1, acc10, 0, 0, 0);
            acc11 = __builtin_amdgcn_mfma_f32_16x16x32_bf16(ah[i], bl1, acc11, 0, 0, 0);
        }

        // split-K partial -> zS[kh], rows rt*16+lq*4+r, cols ct*16+lc
#pragma unroll
        for (int r = 0; r < 4; ++r) {
            int rowoff = kh * 1152 + (rt * 16 + lq * 4 + r) * 36;
            zS[rowoff + lc]      = acc00[r] + acc01[r];
            zS[rowoff + 16 + lc] = acc10[r] + acc11[r];
        }
        __syncthreads();

        // elementwise: thread t owns (b_el, unit u_el); sum the 2 K-halves
        const float* z0 = zS + b_l * 36;
        const float* z1 = zS + 1152 + b_l * 36;
        float zi = bf2f(gvi) + z0[u_el]      + z1[u_el];
        float zf = bf2f(gvf) + z0[8 + u_el]  + z1[8 + u_el];
        float zg = bf2f(gvg) + z0[16 + u_el] + z1[16 + u_el];
        float zo = bf2f(gvo) + z0[24 + u_el] + z1[24 + u_el];

        float ig = sigm_fast(zi);
        float fg = sigm_fast(zf);
        float gg = tanh_fast(zg);
        float og = sigm_fast(zo);

        c_state = fg * c_state + ig * gg;
        float nh = og * tanh_fast(c_state);

        if (step == 511) {
            out[(size_t)step * 65536 + b_el * 1024 + j] = nh;
            break;                      // no publish/barrier needed
        }

        // publish h (bf16 hi only, sc1 -> IF$, packed pairs via shfl)
        unsigned int hiw = f2bf(nh);
        unsigned int hi_o = (unsigned int)__shfl_xor((int)hiw, 1);
        if ((t & 1) == 0) {
            int p32 = (jg * 64 + b_el) * 4 + (u_el >> 1);
            __hip_atomic_store(nH + p32, (hiw & 0xffffu) | (hi_o << 16),
                               __ATOMIC_RELAXED, __HIP_MEMORY_SCOPE_AGENT);
        }

        // barrier: arrive (publishes drained), deferred out store, poll
        asm volatile("s_waitcnt vmcnt(0)" ::: "memory");
        __syncthreads();
        unsigned int target = (unsigned int)(step + 2);
        if (t == 0)
            __hip_atomic_store(&flags[wgid * 32], target, __ATOMIC_RELAXED,
                               __HIP_MEMORY_SCOPE_AGENT);
        out[(size_t)step * 65536 + b_el * 1024 + j] = nh;   // drains next step
        while (__hip_atomic_load(&flags[t * 32], __ATOMIC_RELAXED,
                                 __HIP_MEMORY_SCOPE_AGENT) < target) {}
        __syncthreads();
        asm volatile("" ::: "memory");
    }
}

// ---------------------------------------------------------------------------
extern "C" void kernel_launch(void* const* d_in, const int* in_sizes, int n_in,
                              void* d_out, int out_size, void* d_ws, size_t ws_size,
                              hipStream_t stream)
{
    const float* x  = (const float*)d_in[0];
    const float* h0 = (const float*)d_in[1];
    const float* c0 = (const float*)d_in[2];
    const float* Wi = (const float*)d_in[3];
    const float* Wh = (const float*)d_in[4];
    const float* bb = (const float*)d_in[5];
    float* out = (float*)d_out;

    // ws layout: hp0/hp1 (128KB each) | flags 32KB | WiHi 8MB | WiLo 8MB | G2 268MB
    unsigned int* hp0 = (unsigned int*)d_ws;
    unsigned int* hp1 = hp0 + 32768;
    unsigned int* flags = hp1 + 32768;          // 256 * 32 u32 = 32KB
    unsigned short* WiHi = (unsigned short*)(flags + 8192);
    unsigned short* WiLo = WiHi + 4194304;
    unsigned short* G2 = WiLo + 4194304;

    hipMemsetAsync(flags, 0, 8192 * sizeof(unsigned int), stream);
    wi_pack<<<dim3(1024), dim3(256), 0, stream>>>(Wi, WiHi, WiLo);
    xwi_gemm_mfma<<<dim3(8192), dim3(256), 0, stream>>>(x, WiHi, WiLo, bb, G2);

    void* args[] = {(void*)&G2, (void*)&Wh, (void*)&h0, (void*)&c0, (void*)&out,
                    (void*)&hp0, (void*)&hp1, (void*)&flags};
    hipLaunchCooperativeKernel(reinterpret_cast<void*>(&lstm_scan_mfma),
                               dim3(256), dim3(256), args, 0, stream);
}

// Round 14
// 2795.161 us; speedup vs baseline: 2.0018x; 1.1321x over previous
//
#include <hip/hip_runtime.h>
#include <hip/hip_bf16.h>

// T=512, B=64, D=1024, H=1024, 4H=4096
// Pass 0: pack Wi -> split-bf16 (hi/lo) in MFMA B-fragment order (ws, 16MB)
// Pass 1: G2 = x @ Wi + b via split-bf16 MFMA, scan-native layout:
//         G2[((step*64 + jg)*4 + bh)*1024 + gate*256 + b_l*16 + u]  (bf16)
// Pass 2: cooperative scan, 256 WGs (64 jg x 4 bh). ROUND-14 tile:
//         16 rows x 64 cols per WG; waves split K 4-ways, each reads a
//         DISTINCT 16-row x K-quarter h block -> sc1 broadcast 16 -> 8 MB/step.
//         Wh hi-only in LDS (128 KB; halves MFMA count; ~1e-3 z-noise, well
//         within the 0.0183 threshold vs current 0.0039). Split-K via 4 zS
//         planes (f32, pad 18). Barrier/schedule = round-9/13 verified.

typedef __attribute__((ext_vector_type(8))) short bf16x8;
typedef __attribute__((ext_vector_type(8))) unsigned short ushx8;
typedef __attribute__((ext_vector_type(4))) unsigned short ushx4;
typedef __attribute__((ext_vector_type(4))) float f32x4;
typedef __attribute__((ext_vector_type(2))) unsigned long long u64x2;

static __device__ __forceinline__ unsigned short f2bf(float x) {
    __hip_bfloat16 h = __float2bfloat16(x);
    return __builtin_bit_cast(unsigned short, h);
}
static __device__ __forceinline__ float bf2f(unsigned short u) {
    __hip_bfloat16 h = __builtin_bit_cast(__hip_bfloat16, u);
    return __bfloat162float(h);
}

// coherent (agent-scope, L2-bypassing) 16B load as 2 x u64 relaxed atomics
static __device__ __forceinline__ bf16x8 ld_h16(const unsigned long long* p) {
    unsigned long long a = __hip_atomic_load(p,     __ATOMIC_RELAXED, __HIP_MEMORY_SCOPE_AGENT);
    unsigned long long b = __hip_atomic_load(p + 1, __ATOMIC_RELAXED, __HIP_MEMORY_SCOPE_AGENT);
    u64x2 v; v.x = a; v.y = b;
    return __builtin_bit_cast(bf16x8, v);
}

static __device__ __forceinline__ void gl_lds16(const void* g, void* l) {
    __builtin_amdgcn_global_load_lds(
        (const __attribute__((address_space(1))) unsigned int*)g,
        (__attribute__((address_space(3))) unsigned int*)l, 16, 0, 0);
}

static __device__ __forceinline__ float sigm_fast(float x) {
    return 1.f / (1.f + __expf(-x));
}
static __device__ __forceinline__ float tanh_fast(float x) {
    float e = __expf(2.f * x);
    return 1.f - 2.f / (e + 1.f);
}

// ---------------------------------------------------------------------------
// Pass 0: pack Wi[1024][4096] f32 -> WiHi/WiLo bf16 in B-fragment order.
// ---------------------------------------------------------------------------
__global__ __launch_bounds__(256)
void wi_pack(const float* __restrict__ Wi, unsigned short* __restrict__ WiHi,
             unsigned short* __restrict__ WiLo)
{
    const int bid = blockIdx.x;            // 1024 = tn(32) x kb(32)
    const int tn = bid >> 5, kb = bid & 31;
    const int t = threadIdx.x;
    const int c = t & 127, ko = t >> 7;
    const float* src = Wi + (size_t)(kb * 32 + ko * 16) * 4096 + tn * 128 + c;
    const size_t dbase = ((size_t)(tn * 32 + kb)) * 4096 + c * 8;
#pragma unroll
    for (int o = 0; o < 2; ++o) {
        ushx8 hv, lv;
#pragma unroll
        for (int q = 0; q < 8; ++q) {
            float v = src[(size_t)(o * 8 + q) * 4096];
            unsigned short h = f2bf(v);
            hv[q] = h; lv[q] = f2bf(v - bf2f(h));
        }
        int kq = ko * 2 + o;
        *(ushx8*)(WiHi + dbase + kq * 1024) = hv;
        *(ushx8*)(WiLo + dbase + kq * 1024) = lv;
    }
}

// ---------------------------------------------------------------------------
// Pass 1: G2 = x @ Wi + bias, split-bf16 MFMA, 128x128 tile, BK=32, 4 waves.
// Epilogue writes the round-14 scan-native layout.
// ---------------------------------------------------------------------------
__global__ __launch_bounds__(256)
void xwi_gemm_mfma(const float* __restrict__ x,
                   const unsigned short* __restrict__ WiHi,
                   const unsigned short* __restrict__ WiLo,
                   const float* __restrict__ bias,
                   unsigned short* __restrict__ G2)
{
    __shared__ __align__(16) unsigned short AHi[4096], ALo[4096];
    __shared__ __align__(16) unsigned short BHi[4096], BLo[4096];
    const int bid = blockIdx.x;
    const int bm = bid >> 5, bn = bid & 31;
    const int m0 = bm << 7, n0 = bn << 7;
    const int t = threadIdx.x;
    const int w = t >> 6, l = t & 63, lq = l >> 4, lc = l & 15;
    const int wm = w >> 1, wn = w & 1;

    f32x4 acc[4][4] = {};
    const int row = t >> 1, kh = t & 1;
    const float* xrow = x + (size_t)(m0 + row) * 1024 + kh * 16;
    const unsigned short* bHsl = WiHi + (size_t)(bn * 32) * 4096;
    const unsigned short* bLsl = WiLo + (size_t)(bn * 32) * 4096;

    for (int kb = 0; kb < 32; ++kb) {
        float4 f0 = *(const float4*)(xrow + kb * 32 + 0);
        float4 f1 = *(const float4*)(xrow + kb * 32 + 4);
        float4 f2 = *(const float4*)(xrow + kb * 32 + 8);
        float4 f3 = *(const float4*)(xrow + kb * 32 + 12);
        float fs[16] = {f0.x, f0.y, f0.z, f0.w, f1.x, f1.y, f1.z, f1.w,
                        f2.x, f2.y, f2.z, f2.w, f3.x, f3.y, f3.z, f3.w};
#pragma unroll
        for (int o = 0; o < 2; ++o) {
            ushx8 hv, lv;
#pragma unroll
            for (int q = 0; q < 8; ++q) {
                float v = fs[o * 8 + q];
                unsigned short h = f2bf(v);
                hv[q] = h; lv[q] = f2bf(v - bf2f(h));
            }
            int kq = kh * 2 + o;
            *(ushx8*)&AHi[kq * 1024 + row * 8] = hv;
            *(ushx8*)&ALo[kq * 1024 + row * 8] = lv;
        }
        {
            const unsigned short* sH = bHsl + (size_t)kb * 4096;
            const unsigned short* sL = bLsl + (size_t)kb * 4096;
            gl_lds16(sH + (size_t)(w * 128 + l) * 8,      &BHi[(w * 128) * 8]);
            gl_lds16(sH + (size_t)(w * 128 + 64 + l) * 8, &BHi[(w * 128 + 64) * 8]);
            gl_lds16(sL + (size_t)(w * 128 + l) * 8,      &BLo[(w * 128) * 8]);
            gl_lds16(sL + (size_t)(w * 128 + 64 + l) * 8, &BLo[(w * 128 + 64) * 8]);
        }
        __syncthreads();

        bf16x8 xh[4], xl[4], wh_[4], wl_[4];
#pragma unroll
        for (int a = 0; a < 4; ++a) {
            int off = lq * 1024 + (wm * 64 + a * 16 + lc) * 8;
            xh[a] = *(const bf16x8*)&AHi[off];
            xl[a] = *(const bf16x8*)&ALo[off];
        }
#pragma unroll
        for (int b = 0; b < 4; ++b) {
            int off = lq * 1024 + (wn * 64 + b * 16 + lc) * 8;
            wh_[b] = *(const bf16x8*)&BHi[off];
            wl_[b] = *(const bf16x8*)&BLo[off];
        }
#pragma unroll
        for (int a = 0; a < 4; ++a)
#pragma unroll
            for (int b = 0; b < 4; ++b) {
                acc[a][b] = __builtin_amdgcn_mfma_f32_16x16x32_bf16(wh_[b], xh[a], acc[a][b], 0, 0, 0);
                acc[a][b] = __builtin_amdgcn_mfma_f32_16x16x32_bf16(wl_[b], xh[a], acc[a][b], 0, 0, 0);
                acc[a][b] = __builtin_amdgcn_mfma_f32_16x16x32_bf16(wh_[b], xl[a], acc[a][b], 0, 0, 0);
            }
        __syncthreads();
    }

    float bv[4][4];
#pragma unroll
    for (int b = 0; b < 4; ++b)
#pragma unroll
        for (int r = 0; r < 4; ++r)
            bv[b][r] = bias[n0 + wn * 64 + b * 16 + lq * 4 + r];
#pragma unroll
    for (int a = 0; a < 4; ++a) {
        int m = m0 + wm * 64 + a * 16 + lc;
        int step = m >> 6, b_abs = m & 63;
        int bh_ = b_abs >> 4, b_l = b_abs & 15;
#pragma unroll
        for (int b = 0; b < 4; ++b) {
            int j_abs = n0 + wn * 64 + b * 16 + lq * 4;
            int gate = j_abs >> 10;
            int hid  = j_abs & 1023;
            int jg_t = hid >> 4, u0 = hid & 15;   // u0 in {0,4,8,12}
            ushx4 sv;
#pragma unroll
            for (int r = 0; r < 4; ++r) sv[r] = f2bf(acc[a][b][r] + bv[b][r]);
            size_t addr = (((size_t)(step * 64 + jg_t) * 4 + bh_) * 1024)
                          + gate * 256 + b_l * 16 + u0;
            *(ushx4*)(G2 + addr) = sv;
        }
    }
}

// ---------------------------------------------------------------------------
// Pass 2: cooperative MFMA scan. 256 WGs x 256 threads (4 waves), 1 WG/CU.
// WG (jg = wgid>>2, bh = wgid&3): batch rows bh*16..+15, units jg*16..+15
// (64 z-cols = 4 gate-tiles of 16). Wave w = K-quarter kh: reads a DISTINCT
// 16-row x 256-k h block. Wh hi-only. Split-K via zS[4][4][16][18].
// ---------------------------------------------------------------------------
__global__ __launch_bounds__(256, 1)
void lstm_scan_mfma(const unsigned short* __restrict__ G2,
                    const float* __restrict__ Wh,
                    const float* __restrict__ h0, const float* __restrict__ c0,
                    float* __restrict__ out,
                    unsigned int* __restrict__ hp0,
                    unsigned int* __restrict__ hp1,
                    unsigned int* __restrict__ flags)
{
    __shared__ __align__(16) unsigned short WhHiS[65536];  // 128 KB, [gate][frag]
    __shared__ float zS[4 * 4 * 16 * 18];                  // 18.4 KB

    const int t    = threadIdx.x;
    const int wgid = blockIdx.x;         // 0..255
    const int jg   = wgid >> 2;          // 0..63
    const int bh   = wgid & 3;           // 0..3
    const int kh = t >> 6, l = t & 63, lq = l >> 4, lc = l & 15;

    // Wh slice -> LDS (once): 64 z-cols (cc = gate*16+u), hi only, B-frag order
    for (int idx = t; idx < 65536; idx += 256) {
        int k = idx >> 6, cc = idx & 63;
        int gate = cc >> 4, u = cc & 15;
        int gcol = gate * 1024 + jg * 16 + u;
        float wv = Wh[(size_t)k * 4096 + gcol];
        int pos = gate * 16384 + (((k >> 5) * 64) + (((k >> 3) & 3) * 16 + u)) * 8 + (k & 7);
        WhHiS[pos] = f2bf(wv);
    }

    // init hp0 from h0 (bf16 hi only, sc1 -> IF$): 128 pairs per WG
    if (t < 128) {
        int idx = wgid * 128 + t;
        int b = idx >> 9, k = (idx & 511) * 2;
        unsigned short h0s = f2bf(h0[b * 1024 + k]);
        unsigned short h1s = f2bf(h0[b * 1024 + k + 1]);
        int p32 = ((k >> 3) * 64 + b) * 4 + ((k & 7) >> 1);
        __hip_atomic_store(hp0 + p32, (unsigned int)h0s | ((unsigned int)h1s << 16),
                           __ATOMIC_RELAXED, __HIP_MEMORY_SCOPE_AGENT);
    }

    const int b_l = t >> 4, u_el = t & 15;
    const int b_el = bh * 16 + b_l;
    const int j = jg * 16 + u_el;
    float c_state = c0[b_el * 1024 + j];

    // initial barrier (round-5/9 form: spread flags, all-thread poll)
    {
        asm volatile("s_waitcnt vmcnt(0)" ::: "memory");
        __syncthreads();
        if (t == 0)
            __hip_atomic_store(&flags[wgid * 32], 1u, __ATOMIC_RELAXED,
                               __HIP_MEMORY_SCOPE_AGENT);
        while (__hip_atomic_load(&flags[t * 32], __ATOMIC_RELAXED,
                                 __HIP_MEMORY_SCOPE_AGENT) < 1u) {}
        __syncthreads();
        asm volatile("" ::: "memory");
    }

    const int arow = bh * 16 + lc;
    for (int step = 0; step < 512; ++step) {
        const unsigned long long* hH =
            (const unsigned long long*)((step & 1) ? hp1 : hp0);
        unsigned int* nH = (step & 1) ? hp0 : hp1;

        // G2 prefetch: contiguous 2KB/WG panel, 4 x 2B per thread (dense)
        size_t pb = (((size_t)(step * 64 + jg) * 4 + bh) * 1024) + t;
        unsigned short gvi = G2[pb];
        unsigned short gvf = G2[pb + 256];
        unsigned short gvg = G2[pb + 512];
        unsigned short gvo = G2[pb + 768];

        // K-quarter loop: 8 kb, distinct (rows x K-quarter) per wave
        bf16x8 ah[8];
#pragma unroll
        for (int i = 0; i < 8; ++i) {
            int kb = kh * 8 + i;
            int a64 = ((kb * 4 + lq) * 64 + arow) * 2;
            ah[i] = ld_h16(hH + a64);
        }

        f32x4 acc[4] = {};
#pragma unroll
        for (int i = 0; i < 8; ++i) {
            int kb = kh * 8 + i;
            int b0 = (kb * 64 + l) * 8;
#pragma unroll
            for (int g = 0; g < 4; ++g) {
                bf16x8 bf = *(const bf16x8*)&WhHiS[g * 16384 + b0];
                acc[g] = __builtin_amdgcn_mfma_f32_16x16x32_bf16(ah[i], bf, acc[g], 0, 0, 0);
            }
        }

        // split-K partial -> zS[kh][g][row][col] (pad 18: <=2-way banks)
#pragma unroll
        for (int g = 0; g < 4; ++g)
#pragma unroll
            for (int r = 0; r < 4; ++r)
                zS[((kh * 4 + g) * 16 + lq * 4 + r) * 18 + lc] = acc[g][r];
        __syncthreads();

        // elementwise: thread owns (b_el, j); sum the 4 K-quarters per gate
        float zi = bf2f(gvi), zf = bf2f(gvf), zg = bf2f(gvg), zo = bf2f(gvo);
#pragma unroll
        for (int q = 0; q < 4; ++q) {
            const float* zq = zS + (q * 4 * 16) * 18;
            zi += zq[(0 * 16 + b_l) * 18 + u_el];
            zf += zq[(1 * 16 + b_l) * 18 + u_el];
            zg += zq[(2 * 16 + b_l) * 18 + u_el];
            zo += zq[(3 * 16 + b_l) * 18 + u_el];
        }

        float ig = sigm_fast(zi);
        float fg = sigm_fast(zf);
        float gg = tanh_fast(zg);
        float og = sigm_fast(zo);

        c_state = fg * c_state + ig * gg;
        float nh = og * tanh_fast(c_state);

        if (step == 511) {
            out[(size_t)step * 65536 + b_el * 1024 + j] = nh;
            break;                      // no publish/barrier needed
        }

        // publish h (bf16 hi only, sc1 -> IF$, packed pairs via shfl)
        unsigned int hiw = f2bf(nh);
        unsigned int hi_o = (unsigned int)__shfl_xor((int)hiw, 1);
        if ((t & 1) == 0) {
            int p32 = ((j >> 3) * 64 + b_el) * 4 + ((j & 7) >> 1);
            __hip_atomic_store(nH + p32, (hiw & 0xffffu) | (hi_o << 16),
                               __ATOMIC_RELAXED, __HIP_MEMORY_SCOPE_AGENT);
        }

        // barrier: arrive (publishes drained), deferred out store, poll
        asm volatile("s_waitcnt vmcnt(0)" ::: "memory");
        __syncthreads();
        unsigned int target = (unsigned int)(step + 2);
        if (t == 0)
            __hip_atomic_store(&flags[wgid * 32], target, __ATOMIC_RELAXED,
                               __HIP_MEMORY_SCOPE_AGENT);
        out[(size_t)step * 65536 + b_el * 1024 + j] = nh;   // drains next step
        while (__hip_atomic_load(&flags[t * 32], __ATOMIC_RELAXED,
                                 __HIP_MEMORY_SCOPE_AGENT) < target) {}
        __syncthreads();
        asm volatile("" ::: "memory");
    }
}

// ---------------------------------------------------------------------------
extern "C" void kernel_launch(void* const* d_in, const int* in_sizes, int n_in,
                              void* d_out, int out_size, void* d_ws, size_t ws_size,
                              hipStream_t stream)
{
    const float* x  = (const float*)d_in[0];
    const float* h0 = (const float*)d_in[1];
    const float* c0 = (const float*)d_in[2];
    const float* Wi = (const float*)d_in[3];
    const float* Wh = (const float*)d_in[4];
    const float* bb = (const float*)d_in[5];
    float* out = (float*)d_out;

    // ws layout: hp0/hp1 (128KB each) | flags 32KB | WiHi 8MB | WiLo 8MB | G2 268MB
    unsigned int* hp0 = (unsigned int*)d_ws;
    unsigned int* hp1 = hp0 + 32768;
    unsigned int* flags = hp1 + 32768;          // 256 * 32 u32 = 32KB
    unsigned short* WiHi = (unsigned short*)(flags + 8192);
    unsigned short* WiLo = WiHi + 4194304;
    unsigned short* G2 = WiLo + 4194304;

    hipMemsetAsync(flags, 0, 8192 * sizeof(unsigned int), stream);
    wi_pack<<<dim3(1024), dim3(256), 0, stream>>>(Wi, WiHi, WiLo);
    xwi_gemm_mfma<<<dim3(8192), dim3(256), 0, stream>>>(x, WiHi, WiLo, bb, G2);

    void* args[] = {(void*)&G2, (void*)&Wh, (void*)&h0, (void*)&c0, (void*)&out,
                    (void*)&hp0, (void*)&hp1, (void*)&flags};
    hipLaunchCooperativeKernel(reinterpret_cast<void*>(&lstm_scan_mfma),
                               dim3(256), dim3(256), args, 0, stream);
}

// Round 15
// 2677.486 us; speedup vs baseline: 2.0897x; 1.0439x over previous
//
#include <hip/hip_runtime.h>
#include <hip/hip_bf16.h>

// T=512, B=64, D=1024, H=1024, 4H=4096
// Pass 0: pack Wi -> bf16 (hi only, round-15) in MFMA B-fragment order (8MB)
// Pass 1: G2 = x @ Wi + b, x split-bf16 (hi+lo) x Wi-hi => 2 MFMA passes.
// Pass 2: cooperative scan (round-14 verified, untouched): 256 WGs
//         (64 jg x 4 bh), 16 rows x 64 cols per WG, waves split K 4-ways,
//         sc1 h broadcast 8 MB/step, Wh hi-only in LDS, split-K via 4 zS
//         planes, round-9 barrier.

typedef __attribute__((ext_vector_type(8))) short bf16x8;
typedef __attribute__((ext_vector_type(8))) unsigned short ushx8;
typedef __attribute__((ext_vector_type(4))) unsigned short ushx4;
typedef __attribute__((ext_vector_type(4))) float f32x4;
typedef __attribute__((ext_vector_type(2))) unsigned long long u64x2;

static __device__ __forceinline__ unsigned short f2bf(float x) {
    __hip_bfloat16 h = __float2bfloat16(x);
    return __builtin_bit_cast(unsigned short, h);
}
static __device__ __forceinline__ float bf2f(unsigned short u) {
    __hip_bfloat16 h = __builtin_bit_cast(__hip_bfloat16, u);
    return __bfloat162float(h);
}

// coherent (agent-scope, L2-bypassing) 16B load as 2 x u64 relaxed atomics
static __device__ __forceinline__ bf16x8 ld_h16(const unsigned long long* p) {
    unsigned long long a = __hip_atomic_load(p,     __ATOMIC_RELAXED, __HIP_MEMORY_SCOPE_AGENT);
    unsigned long long b = __hip_atomic_load(p + 1, __ATOMIC_RELAXED, __HIP_MEMORY_SCOPE_AGENT);
    u64x2 v; v.x = a; v.y = b;
    return __builtin_bit_cast(bf16x8, v);
}

static __device__ __forceinline__ void gl_lds16(const void* g, void* l) {
    __builtin_amdgcn_global_load_lds(
        (const __attribute__((address_space(1))) unsigned int*)g,
        (__attribute__((address_space(3))) unsigned int*)l, 16, 0, 0);
}

static __device__ __forceinline__ float sigm_fast(float x) {
    return 1.f / (1.f + __expf(-x));
}
static __device__ __forceinline__ float tanh_fast(float x) {
    float e = __expf(2.f * x);
    return 1.f - 2.f / (e + 1.f);
}

// ---------------------------------------------------------------------------
// Pass 0: pack Wi[1024][4096] f32 -> WiHi bf16 (hi only), B-fragment order.
// ---------------------------------------------------------------------------
__global__ __launch_bounds__(256)
void wi_pack(const float* __restrict__ Wi, unsigned short* __restrict__ WiHi)
{
    const int bid = blockIdx.x;            // 1024 = tn(32) x kb(32)
    const int tn = bid >> 5, kb = bid & 31;
    const int t = threadIdx.x;
    const int c = t & 127, ko = t >> 7;
    const float* src = Wi + (size_t)(kb * 32 + ko * 16) * 4096 + tn * 128 + c;
    const size_t dbase = ((size_t)(tn * 32 + kb)) * 4096 + c * 8;
#pragma unroll
    for (int o = 0; o < 2; ++o) {
        ushx8 hv;
#pragma unroll
        for (int q = 0; q < 8; ++q)
            hv[q] = f2bf(src[(size_t)(o * 8 + q) * 4096]);
        int kq = ko * 2 + o;
        *(ushx8*)(WiHi + dbase + kq * 1024) = hv;
    }
}

// ---------------------------------------------------------------------------
// Pass 1: G2 = x @ Wi + bias; x split hi/lo, Wi hi-only (2 MFMA passes).
// 128x128 tile, BK=32, 4 waves. Epilogue writes round-14 scan-native layout.
// ---------------------------------------------------------------------------
__global__ __launch_bounds__(256)
void xwi_gemm_mfma(const float* __restrict__ x,
                   const unsigned short* __restrict__ WiHi,
                   const float* __restrict__ bias,
                   unsigned short* __restrict__ G2)
{
    __shared__ __align__(16) unsigned short AHi[4096], ALo[4096];
    __shared__ __align__(16) unsigned short BHi[4096];
    const int bid = blockIdx.x;
    const int bm = bid >> 5, bn = bid & 31;
    const int m0 = bm << 7, n0 = bn << 7;
    const int t = threadIdx.x;
    const int w = t >> 6, l = t & 63, lq = l >> 4, lc = l & 15;
    const int wm = w >> 1, wn = w & 1;

    f32x4 acc[4][4] = {};
    const int row = t >> 1, kh = t & 1;
    const float* xrow = x + (size_t)(m0 + row) * 1024 + kh * 16;
    const unsigned short* bHsl = WiHi + (size_t)(bn * 32) * 4096;

    for (int kb = 0; kb < 32; ++kb) {
        float4 f0 = *(const float4*)(xrow + kb * 32 + 0);
        float4 f1 = *(const float4*)(xrow + kb * 32 + 4);
        float4 f2 = *(const float4*)(xrow + kb * 32 + 8);
        float4 f3 = *(const float4*)(xrow + kb * 32 + 12);
        float fs[16] = {f0.x, f0.y, f0.z, f0.w, f1.x, f1.y, f1.z, f1.w,
                        f2.x, f2.y, f2.z, f2.w, f3.x, f3.y, f3.z, f3.w};
#pragma unroll
        for (int o = 0; o < 2; ++o) {
            ushx8 hv, lv;
#pragma unroll
            for (int q = 0; q < 8; ++q) {
                float v = fs[o * 8 + q];
                unsigned short h = f2bf(v);
                hv[q] = h; lv[q] = f2bf(v - bf2f(h));
            }
            int kq = kh * 2 + o;
            *(ushx8*)&AHi[kq * 1024 + row * 8] = hv;
            *(ushx8*)&ALo[kq * 1024 + row * 8] = lv;
        }
        {
            const unsigned short* sH = bHsl + (size_t)kb * 4096;
            gl_lds16(sH + (size_t)(w * 128 + l) * 8,      &BHi[(w * 128) * 8]);
            gl_lds16(sH + (size_t)(w * 128 + 64 + l) * 8, &BHi[(w * 128 + 64) * 8]);
        }
        __syncthreads();

        bf16x8 xh[4], xl[4], wh_[4];
#pragma unroll
        for (int a = 0; a < 4; ++a) {
            int off = lq * 1024 + (wm * 64 + a * 16 + lc) * 8;
            xh[a] = *(const bf16x8*)&AHi[off];
            xl[a] = *(const bf16x8*)&ALo[off];
        }
#pragma unroll
        for (int b = 0; b < 4; ++b) {
            int off = lq * 1024 + (wn * 64 + b * 16 + lc) * 8;
            wh_[b] = *(const bf16x8*)&BHi[off];
        }
#pragma unroll
        for (int a = 0; a < 4; ++a)
#pragma unroll
            for (int b = 0; b < 4; ++b) {
                acc[a][b] = __builtin_amdgcn_mfma_f32_16x16x32_bf16(wh_[b], xh[a], acc[a][b], 0, 0, 0);
                acc[a][b] = __builtin_amdgcn_mfma_f32_16x16x32_bf16(wh_[b], xl[a], acc[a][b], 0, 0, 0);
            }
        __syncthreads();
    }

    float bv[4][4];
#pragma unroll
    for (int b = 0; b < 4; ++b)
#pragma unroll
        for (int r = 0; r < 4; ++r)
            bv[b][r] = bias[n0 + wn * 64 + b * 16 + lq * 4 + r];
#pragma unroll
    for (int a = 0; a < 4; ++a) {
        int m = m0 + wm * 64 + a * 16 + lc;
        int step = m >> 6, b_abs = m & 63;
        int bh_ = b_abs >> 4, b_l = b_abs & 15;
#pragma unroll
        for (int b = 0; b < 4; ++b) {
            int j_abs = n0 + wn * 64 + b * 16 + lq * 4;
            int gate = j_abs >> 10;
            int hid  = j_abs & 1023;
            int jg_t = hid >> 4, u0 = hid & 15;   // u0 in {0,4,8,12}
            ushx4 sv;
#pragma unroll
            for (int r = 0; r < 4; ++r) sv[r] = f2bf(acc[a][b][r] + bv[b][r]);
            size_t addr = (((size_t)(step * 64 + jg_t) * 4 + bh_) * 1024)
                          + gate * 256 + b_l * 16 + u0;
            *(ushx4*)(G2 + addr) = sv;
        }
    }
}

// ---------------------------------------------------------------------------
// Pass 2: cooperative MFMA scan (round-14 verified, unchanged).
// ---------------------------------------------------------------------------
__global__ __launch_bounds__(256, 1)
void lstm_scan_mfma(const unsigned short* __restrict__ G2,
                    const float* __restrict__ Wh,
                    const float* __restrict__ h0, const float* __restrict__ c0,
                    float* __restrict__ out,
                    unsigned int* __restrict__ hp0,
                    unsigned int* __restrict__ hp1,
                    unsigned int* __restrict__ flags)
{
    __shared__ __align__(16) unsigned short WhHiS[65536];  // 128 KB, [gate][frag]
    __shared__ float zS[4 * 4 * 16 * 18];                  // 18.4 KB

    const int t    = threadIdx.x;
    const int wgid = blockIdx.x;         // 0..255
    const int jg   = wgid >> 2;          // 0..63
    const int bh   = wgid & 3;           // 0..3
    const int kh = t >> 6, l = t & 63, lq = l >> 4, lc = l & 15;

    // Wh slice -> LDS (once): 64 z-cols (cc = gate*16+u), hi only, B-frag order
    for (int idx = t; idx < 65536; idx += 256) {
        int k = idx >> 6, cc = idx & 63;
        int gate = cc >> 4, u = cc & 15;
        int gcol = gate * 1024 + jg * 16 + u;
        float wv = Wh[(size_t)k * 4096 + gcol];
        int pos = gate * 16384 + (((k >> 5) * 64) + (((k >> 3) & 3) * 16 + u)) * 8 + (k & 7);
        WhHiS[pos] = f2bf(wv);
    }

    // init hp0 from h0 (bf16 hi only, sc1 -> IF$): 128 pairs per WG
    if (t < 128) {
        int idx = wgid * 128 + t;
        int b = idx >> 9, k = (idx & 511) * 2;
        unsigned short h0s = f2bf(h0[b * 1024 + k]);
        unsigned short h1s = f2bf(h0[b * 1024 + k + 1]);
        int p32 = ((k >> 3) * 64 + b) * 4 + ((k & 7) >> 1);
        __hip_atomic_store(hp0 + p32, (unsigned int)h0s | ((unsigned int)h1s << 16),
                           __ATOMIC_RELAXED, __HIP_MEMORY_SCOPE_AGENT);
    }

    const int b_l = t >> 4, u_el = t & 15;
    const int b_el = bh * 16 + b_l;
    const int j = jg * 16 + u_el;
    float c_state = c0[b_el * 1024 + j];

    // initial barrier (round-5/9 form: spread flags, all-thread poll)
    {
        asm volatile("s_waitcnt vmcnt(0)" ::: "memory");
        __syncthreads();
        if (t == 0)
            __hip_atomic_store(&flags[wgid * 32], 1u, __ATOMIC_RELAXED,
                               __HIP_MEMORY_SCOPE_AGENT);
        while (__hip_atomic_load(&flags[t * 32], __ATOMIC_RELAXED,
                                 __HIP_MEMORY_SCOPE_AGENT) < 1u) {}
        __syncthreads();
        asm volatile("" ::: "memory");
    }

    const int arow = bh * 16 + lc;
    for (int step = 0; step < 512; ++step) {
        const unsigned long long* hH =
            (const unsigned long long*)((step & 1) ? hp1 : hp0);
        unsigned int* nH = (step & 1) ? hp0 : hp1;

        // G2 prefetch: contiguous 2KB/WG panel, 4 x 2B per thread (dense)
        size_t pb = (((size_t)(step * 64 + jg) * 4 + bh) * 1024) + t;
        unsigned short gvi = G2[pb];
        unsigned short gvf = G2[pb + 256];
        unsigned short gvg = G2[pb + 512];
        unsigned short gvo = G2[pb + 768];

        // K-quarter loop: 8 kb, distinct (rows x K-quarter) per wave
        bf16x8 ah[8];
#pragma unroll
        for (int i = 0; i < 8; ++i) {
            int kb = kh * 8 + i;
            int a64 = ((kb * 4 + lq) * 64 + arow) * 2;
            ah[i] = ld_h16(hH + a64);
        }

        f32x4 acc[4] = {};
#pragma unroll
        for (int i = 0; i < 8; ++i) {
            int kb = kh * 8 + i;
            int b0 = (kb * 64 + l) * 8;
#pragma unroll
            for (int g = 0; g < 4; ++g) {
                bf16x8 bf = *(const bf16x8*)&WhHiS[g * 16384 + b0];
                acc[g] = __builtin_amdgcn_mfma_f32_16x16x32_bf16(ah[i], bf, acc[g], 0, 0, 0);
            }
        }

        // split-K partial -> zS[kh][g][row][col] (pad 18: <=2-way banks)
#pragma unroll
        for (int g = 0; g < 4; ++g)
#pragma unroll
            for (int r = 0; r < 4; ++r)
                zS[((kh * 4 + g) * 16 + lq * 4 + r) * 18 + lc] = acc[g][r];
        __syncthreads();

        // elementwise: thread owns (b_el, j); sum the 4 K-quarters per gate
        float zi = bf2f(gvi), zf = bf2f(gvf), zg = bf2f(gvg), zo = bf2f(gvo);
#pragma unroll
        for (int q = 0; q < 4; ++q) {
            const float* zq = zS + (q * 4 * 16) * 18;
            zi += zq[(0 * 16 + b_l) * 18 + u_el];
            zf += zq[(1 * 16 + b_l) * 18 + u_el];
            zg += zq[(2 * 16 + b_l) * 18 + u_el];
            zo += zq[(3 * 16 + b_l) * 18 + u_el];
        }

        float ig = sigm_fast(zi);
        float fg = sigm_fast(zf);
        float gg = tanh_fast(zg);
        float og = sigm_fast(zo);

        c_state = fg * c_state + ig * gg;
        float nh = og * tanh_fast(c_state);

        if (step == 511) {
            out[(size_t)step * 65536 + b_el * 1024 + j] = nh;
            break;                      // no publish/barrier needed
        }

        // publish h (bf16 hi only, sc1 -> IF$, packed pairs via shfl)
        unsigned int hiw = f2bf(nh);
        unsigned int hi_o = (unsigned int)__shfl_xor((int)hiw, 1);
        if ((t & 1) == 0) {
            int p32 = ((j >> 3) * 64 + b_el) * 4 + ((j & 7) >> 1);
            __hip_atomic_store(nH + p32, (hiw & 0xffffu) | (hi_o << 16),
                               __ATOMIC_RELAXED, __HIP_MEMORY_SCOPE_AGENT);
        }

        // barrier: arrive (publishes drained), deferred out store, poll
        asm volatile("s_waitcnt vmcnt(0)" ::: "memory");
        __syncthreads();
        unsigned int target = (unsigned int)(step + 2);
        if (t == 0)
            __hip_atomic_store(&flags[wgid * 32], target, __ATOMIC_RELAXED,
                               __HIP_MEMORY_SCOPE_AGENT);
        out[(size_t)step * 65536 + b_el * 1024 + j] = nh;   // drains next step
        while (__hip_atomic_load(&flags[t * 32], __ATOMIC_RELAXED,
                                 __HIP_MEMORY_SCOPE_AGENT) < target) {}
        __syncthreads();
        asm volatile("" ::: "memory");
    }
}

// ---------------------------------------------------------------------------
extern "C" void kernel_launch(void* const* d_in, const int* in_sizes, int n_in,
                              void* d_out, int out_size, void* d_ws, size_t ws_size,
                              hipStream_t stream)
{
    const float* x  = (const float*)d_in[0];
    const float* h0 = (const float*)d_in[1];
    const float* c0 = (const float*)d_in[2];
    const float* Wi = (const float*)d_in[3];
    const float* Wh = (const float*)d_in[4];
    const float* bb = (const float*)d_in[5];
    float* out = (float*)d_out;

    // ws layout: hp0/hp1 (128KB each) | flags 32KB | WiHi 8MB | G2 268MB
    unsigned int* hp0 = (unsigned int*)d_ws;
    unsigned int* hp1 = hp0 + 32768;
    unsigned int* flags = hp1 + 32768;          // 256 * 32 u32 = 32KB
    unsigned short* WiHi = (unsigned short*)(flags + 8192);
    unsigned short* G2 = WiHi + 4194304;

    hipMemsetAsync(flags, 0, 8192 * sizeof(unsigned int), stream);
    wi_pack<<<dim3(1024), dim3(256), 0, stream>>>(Wi, WiHi);
    xwi_gemm_mfma<<<dim3(8192), dim3(256), 0, stream>>>(x, WiHi, bb, G2);

    void* args[] = {(void*)&G2, (void*)&Wh, (void*)&h0, (void*)&c0, (void*)&out,
                    (void*)&hp0, (void*)&hp1, (void*)&flags};
    hipLaunchCooperativeKernel(reinterpret_cast<void*>(&lstm_scan_mfma),
                               dim3(256), dim3(256), args, 0, stream);
}

// Round 16
// 2205.294 us; speedup vs baseline: 2.5372x; 1.2141x over previous
//
#include <hip/hip_runtime.h>
#include <hip/hip_bf16.h>

// T=512, B=64, D=1024, H=1024, 4H=4096
// Pass 0a: pack Wi -> bf16 hi, MFMA B-fragment slab order (8MB)
// Pass 0b: pack x  -> bf16 hi, MFMA A-fragment slab order (64MB)  [round-16]
// Pass 1 : G2 = x @ Wi + b, SINGLE bf16 MFMA pass, both operands staged via
//          global_load_lds (no VALU conversion in the hot loop). [round-16]
// Pass 2 : cooperative scan (round-14/15 verified, untouched).

typedef __attribute__((ext_vector_type(8))) short bf16x8;
typedef __attribute__((ext_vector_type(8))) unsigned short ushx8;
typedef __attribute__((ext_vector_type(4))) unsigned short ushx4;
typedef __attribute__((ext_vector_type(4))) float f32x4;
typedef __attribute__((ext_vector_type(2))) unsigned long long u64x2;

static __device__ __forceinline__ unsigned short f2bf(float x) {
    __hip_bfloat16 h = __float2bfloat16(x);
    return __builtin_bit_cast(unsigned short, h);
}
static __device__ __forceinline__ float bf2f(unsigned short u) {
    __hip_bfloat16 h = __builtin_bit_cast(__hip_bfloat16, u);
    return __bfloat162float(h);
}

// coherent (agent-scope, L2-bypassing) 16B load as 2 x u64 relaxed atomics
static __device__ __forceinline__ bf16x8 ld_h16(const unsigned long long* p) {
    unsigned long long a = __hip_atomic_load(p,     __ATOMIC_RELAXED, __HIP_MEMORY_SCOPE_AGENT);
    unsigned long long b = __hip_atomic_load(p + 1, __ATOMIC_RELAXED, __HIP_MEMORY_SCOPE_AGENT);
    u64x2 v; v.x = a; v.y = b;
    return __builtin_bit_cast(bf16x8, v);
}

static __device__ __forceinline__ void gl_lds16(const void* g, void* l) {
    __builtin_amdgcn_global_load_lds(
        (const __attribute__((address_space(1))) unsigned int*)g,
        (__attribute__((address_space(3))) unsigned int*)l, 16, 0, 0);
}

static __device__ __forceinline__ float sigm_fast(float x) {
    return 1.f / (1.f + __expf(-x));
}
static __device__ __forceinline__ float tanh_fast(float x) {
    float e = __expf(2.f * x);
    return 1.f - 2.f / (e + 1.f);
}

// ---------------------------------------------------------------------------
// Pass 0a: pack Wi[1024][4096] f32 -> WiHi bf16 (hi only), B-fragment slabs.
// Slab (tn, kb) of 4096 shorts: kq*1024 + c*8 + (k&7).
// ---------------------------------------------------------------------------
__global__ __launch_bounds__(256)
void wi_pack(const float* __restrict__ Wi, unsigned short* __restrict__ WiHi)
{
    const int bid = blockIdx.x;            // 1024 = tn(32) x kb(32)
    const int tn = bid >> 5, kb = bid & 31;
    const int t = threadIdx.x;
    const int c = t & 127, ko = t >> 7;
    const float* src = Wi + (size_t)(kb * 32 + ko * 16) * 4096 + tn * 128 + c;
    const size_t dbase = ((size_t)(tn * 32 + kb)) * 4096 + c * 8;
#pragma unroll
    for (int o = 0; o < 2; ++o) {
        ushx8 hv;
#pragma unroll
        for (int q = 0; q < 8; ++q)
            hv[q] = f2bf(src[(size_t)(o * 8 + q) * 4096]);
        int kq = ko * 2 + o;
        *(ushx8*)(WiHi + dbase + kq * 1024) = hv;
    }
}

// ---------------------------------------------------------------------------
// Pass 0b: pack x[32768][1024] f32 -> xHi bf16 (hi only), A-fragment slabs.
// Slab (bm, kb) of 4096 shorts: kq*1024 + row*8 + (k&7), row = m within 128.
// ---------------------------------------------------------------------------
__global__ __launch_bounds__(256)
void x_pack(const float* __restrict__ x, unsigned short* __restrict__ xHi)
{
    const int bid = blockIdx.x;            // 8192 = bm(256) x kb(32)
    const int bm = bid >> 5, kb = bid & 31;
    const int t = threadIdx.x;
    const int row = t >> 1, kh = t & 1;
    const float* src = x + (size_t)(bm * 128 + row) * 1024 + kb * 32 + kh * 16;
    const size_t dbase = ((size_t)(bm * 32 + kb)) * 4096 + row * 8;

    float4 f0 = *(const float4*)(src + 0);
    float4 f1 = *(const float4*)(src + 4);
    float4 f2 = *(const float4*)(src + 8);
    float4 f3 = *(const float4*)(src + 12);
    float fs[16] = {f0.x, f0.y, f0.z, f0.w, f1.x, f1.y, f1.z, f1.w,
                    f2.x, f2.y, f2.z, f2.w, f3.x, f3.y, f3.z, f3.w};
#pragma unroll
    for (int o = 0; o < 2; ++o) {
        ushx8 hv;
#pragma unroll
        for (int q = 0; q < 8; ++q) hv[q] = f2bf(fs[o * 8 + q]);
        int kq = kh * 2 + o;
        *(ushx8*)(xHi + dbase + kq * 1024) = hv;
    }
}

// ---------------------------------------------------------------------------
// Pass 1: G2 = x @ Wi + bias; single bf16 pass, both operands global_load_lds.
// 128x128 tile, BK=32, 4 waves. Epilogue writes round-14 scan-native layout.
// ---------------------------------------------------------------------------
__global__ __launch_bounds__(256)
void xwi_gemm_mfma(const unsigned short* __restrict__ xHi,
                   const unsigned short* __restrict__ WiHi,
                   const float* __restrict__ bias,
                   unsigned short* __restrict__ G2)
{
    __shared__ __align__(16) unsigned short AHi[4096];
    __shared__ __align__(16) unsigned short BHi[4096];
    const int bid = blockIdx.x;
    const int bm = bid >> 5, bn = bid & 31;
    const int m0 = bm << 7, n0 = bn << 7;
    const int t = threadIdx.x;
    const int w = t >> 6, l = t & 63, lq = l >> 4, lc = l & 15;
    const int wm = w >> 1, wn = w & 1;

    f32x4 acc[4][4] = {};
    const unsigned short* aSl = xHi + (size_t)(bm * 32) * 4096;
    const unsigned short* bSl = WiHi + (size_t)(bn * 32) * 4096;

    for (int kb = 0; kb < 32; ++kb) {
        {
            const unsigned short* sA = aSl + (size_t)kb * 4096;
            const unsigned short* sB = bSl + (size_t)kb * 4096;
            gl_lds16(sA + (size_t)(w * 128 + l) * 8,      &AHi[(w * 128) * 8]);
            gl_lds16(sA + (size_t)(w * 128 + 64 + l) * 8, &AHi[(w * 128 + 64) * 8]);
            gl_lds16(sB + (size_t)(w * 128 + l) * 8,      &BHi[(w * 128) * 8]);
            gl_lds16(sB + (size_t)(w * 128 + 64 + l) * 8, &BHi[(w * 128 + 64) * 8]);
        }
        __syncthreads();

        bf16x8 xh[4], wh_[4];
#pragma unroll
        for (int a = 0; a < 4; ++a) {
            int off = lq * 1024 + (wm * 64 + a * 16 + lc) * 8;
            xh[a] = *(const bf16x8*)&AHi[off];
        }
#pragma unroll
        for (int b = 0; b < 4; ++b) {
            int off = lq * 1024 + (wn * 64 + b * 16 + lc) * 8;
            wh_[b] = *(const bf16x8*)&BHi[off];
        }
#pragma unroll
        for (int a = 0; a < 4; ++a)
#pragma unroll
            for (int b = 0; b < 4; ++b)
                acc[a][b] = __builtin_amdgcn_mfma_f32_16x16x32_bf16(wh_[b], xh[a], acc[a][b], 0, 0, 0);
        __syncthreads();
    }

    float bv[4][4];
#pragma unroll
    for (int b = 0; b < 4; ++b)
#pragma unroll
        for (int r = 0; r < 4; ++r)
            bv[b][r] = bias[n0 + wn * 64 + b * 16 + lq * 4 + r];
#pragma unroll
    for (int a = 0; a < 4; ++a) {
        int m = m0 + wm * 64 + a * 16 + lc;
        int step = m >> 6, b_abs = m & 63;
        int bh_ = b_abs >> 4, b_l = b_abs & 15;
#pragma unroll
        for (int b = 0; b < 4; ++b) {
            int j_abs = n0 + wn * 64 + b * 16 + lq * 4;
            int gate = j_abs >> 10;
            int hid  = j_abs & 1023;
            int jg_t = hid >> 4, u0 = hid & 15;   // u0 in {0,4,8,12}
            ushx4 sv;
#pragma unroll
            for (int r = 0; r < 4; ++r) sv[r] = f2bf(acc[a][b][r] + bv[b][r]);
            size_t addr = (((size_t)(step * 64 + jg_t) * 4 + bh_) * 1024)
                          + gate * 256 + b_l * 16 + u0;
            *(ushx4*)(G2 + addr) = sv;
        }
    }
}

// ---------------------------------------------------------------------------
// Pass 2: cooperative MFMA scan (round-14/15 verified, unchanged).
// ---------------------------------------------------------------------------
__global__ __launch_bounds__(256, 1)
void lstm_scan_mfma(const unsigned short* __restrict__ G2,
                    const float* __restrict__ Wh,
                    const float* __restrict__ h0, const float* __restrict__ c0,
                    float* __restrict__ out,
                    unsigned int* __restrict__ hp0,
                    unsigned int* __restrict__ hp1,
                    unsigned int* __restrict__ flags)
{
    __shared__ __align__(16) unsigned short WhHiS[65536];  // 128 KB, [gate][frag]
    __shared__ float zS[4 * 4 * 16 * 18];                  // 18.4 KB

    const int t    = threadIdx.x;
    const int wgid = blockIdx.x;         // 0..255
    const int jg   = wgid >> 2;          // 0..63
    const int bh   = wgid & 3;           // 0..3
    const int kh = t >> 6, l = t & 63, lq = l >> 4, lc = l & 15;

    // Wh slice -> LDS (once): 64 z-cols (cc = gate*16+u), hi only, B-frag order
    for (int idx = t; idx < 65536; idx += 256) {
        int k = idx >> 6, cc = idx & 63;
        int gate = cc >> 4, u = cc & 15;
        int gcol = gate * 1024 + jg * 16 + u;
        float wv = Wh[(size_t)k * 4096 + gcol];
        int pos = gate * 16384 + (((k >> 5) * 64) + (((k >> 3) & 3) * 16 + u)) * 8 + (k & 7);
        WhHiS[pos] = f2bf(wv);
    }

    // init hp0 from h0 (bf16 hi only, sc1 -> IF$): 128 pairs per WG
    if (t < 128) {
        int idx = wgid * 128 + t;
        int b = idx >> 9, k = (idx & 511) * 2;
        unsigned short h0s = f2bf(h0[b * 1024 + k]);
        unsigned short h1s = f2bf(h0[b * 1024 + k + 1]);
        int p32 = ((k >> 3) * 64 + b) * 4 + ((k & 7) >> 1);
        __hip_atomic_store(hp0 + p32, (unsigned int)h0s | ((unsigned int)h1s << 16),
                           __ATOMIC_RELAXED, __HIP_MEMORY_SCOPE_AGENT);
    }

    const int b_l = t >> 4, u_el = t & 15;
    const int b_el = bh * 16 + b_l;
    const int j = jg * 16 + u_el;
    float c_state = c0[b_el * 1024 + j];

    // initial barrier (round-5/9 form: spread flags, all-thread poll)
    {
        asm volatile("s_waitcnt vmcnt(0)" ::: "memory");
        __syncthreads();
        if (t == 0)
            __hip_atomic_store(&flags[wgid * 32], 1u, __ATOMIC_RELAXED,
                               __HIP_MEMORY_SCOPE_AGENT);
        while (__hip_atomic_load(&flags[t * 32], __ATOMIC_RELAXED,
                                 __HIP_MEMORY_SCOPE_AGENT) < 1u) {}
        __syncthreads();
        asm volatile("" ::: "memory");
    }

    const int arow = bh * 16 + lc;
    for (int step = 0; step < 512; ++step) {
        const unsigned long long* hH =
            (const unsigned long long*)((step & 1) ? hp1 : hp0);
        unsigned int* nH = (step & 1) ? hp0 : hp1;

        // G2 prefetch: contiguous 2KB/WG panel, 4 x 2B per thread (dense)
        size_t pb = (((size_t)(step * 64 + jg) * 4 + bh) * 1024) + t;
        unsigned short gvi = G2[pb];
        unsigned short gvf = G2[pb + 256];
        unsigned short gvg = G2[pb + 512];
        unsigned short gvo = G2[pb + 768];

        // K-quarter loop: 8 kb, distinct (rows x K-quarter) per wave
        bf16x8 ah[8];
#pragma unroll
        for (int i = 0; i < 8; ++i) {
            int kb = kh * 8 + i;
            int a64 = ((kb * 4 + lq) * 64 + arow) * 2;
            ah[i] = ld_h16(hH + a64);
        }

        f32x4 acc[4] = {};
#pragma unroll
        for (int i = 0; i < 8; ++i) {
            int kb = kh * 8 + i;
            int b0 = (kb * 64 + l) * 8;
#pragma unroll
            for (int g = 0; g < 4; ++g) {
                bf16x8 bf = *(const bf16x8*)&WhHiS[g * 16384 + b0];
                acc[g] = __builtin_amdgcn_mfma_f32_16x16x32_bf16(ah[i], bf, acc[g], 0, 0, 0);
            }
        }

        // split-K partial -> zS[kh][g][row][col] (pad 18: <=2-way banks)
#pragma unroll
        for (int g = 0; g < 4; ++g)
#pragma unroll
            for (int r = 0; r < 4; ++r)
                zS[((kh * 4 + g) * 16 + lq * 4 + r) * 18 + lc] = acc[g][r];
        __syncthreads();

        // elementwise: thread owns (b_el, j); sum the 4 K-quarters per gate
        float zi = bf2f(gvi), zf = bf2f(gvf), zg = bf2f(gvg), zo = bf2f(gvo);
#pragma unroll
        for (int q = 0; q < 4; ++q) {
            const float* zq = zS + (q * 4 * 16) * 18;
            zi += zq[(0 * 16 + b_l) * 18 + u_el];
            zf += zq[(1 * 16 + b_l) * 18 + u_el];
            zg += zq[(2 * 16 + b_l) * 18 + u_el];
            zo += zq[(3 * 16 + b_l) * 18 + u_el];
        }

        float ig = sigm_fast(zi);
        float fg = sigm_fast(zf);
        float gg = tanh_fast(zg);
        float og = sigm_fast(zo);

        c_state = fg * c_state + ig * gg;
        float nh = og * tanh_fast(c_state);

        if (step == 511) {
            out[(size_t)step * 65536 + b_el * 1024 + j] = nh;
            break;                      // no publish/barrier needed
        }

        // publish h (bf16 hi only, sc1 -> IF$, packed pairs via shfl)
        unsigned int hiw = f2bf(nh);
        unsigned int hi_o = (unsigned int)__shfl_xor((int)hiw, 1);
        if ((t & 1) == 0) {
            int p32 = ((j >> 3) * 64 + b_el) * 4 + ((j & 7) >> 1);
            __hip_atomic_store(nH + p32, (hiw & 0xffffu) | (hi_o << 16),
                               __ATOMIC_RELAXED, __HIP_MEMORY_SCOPE_AGENT);
        }

        // barrier: arrive (publishes drained), deferred out store, poll
        asm volatile("s_waitcnt vmcnt(0)" ::: "memory");
        __syncthreads();
        unsigned int target = (unsigned int)(step + 2);
        if (t == 0)
            __hip_atomic_store(&flags[wgid * 32], target, __ATOMIC_RELAXED,
                               __HIP_MEMORY_SCOPE_AGENT);
        out[(size_t)step * 65536 + b_el * 1024 + j] = nh;   // drains next step
        while (__hip_atomic_load(&flags[t * 32], __ATOMIC_RELAXED,
                                 __HIP_MEMORY_SCOPE_AGENT) < target) {}
        __syncthreads();
        asm volatile("" ::: "memory");
    }
}

// ---------------------------------------------------------------------------
extern "C" void kernel_launch(void* const* d_in, const int* in_sizes, int n_in,
                              void* d_out, int out_size, void* d_ws, size_t ws_size,
                              hipStream_t stream)
{
    const float* x  = (const float*)d_in[0];
    const float* h0 = (const float*)d_in[1];
    const float* c0 = (const float*)d_in[2];
    const float* Wi = (const float*)d_in[3];
    const float* Wh = (const float*)d_in[4];
    const float* bb = (const float*)d_in[5];
    float* out = (float*)d_out;

    // ws layout: hp0/hp1 (128KB each) | flags 32KB | WiHi 8MB | xHi 64MB | G2 268MB
    // (total ~340MB; ws >= 352MB established in round 10)
    unsigned int* hp0 = (unsigned int*)d_ws;
    unsigned int* hp1 = hp0 + 32768;
    unsigned int* flags = hp1 + 32768;          // 256 * 32 u32 = 32KB
    unsigned short* WiHi = (unsigned short*)(flags + 8192);
    unsigned short* xHi = WiHi + 4194304;       // 32768*1024 bf16 = 64MB
    unsigned short* G2 = xHi + 33554432;

    hipMemsetAsync(flags, 0, 8192 * sizeof(unsigned int), stream);
    wi_pack<<<dim3(1024), dim3(256), 0, stream>>>(Wi, WiHi);
    x_pack<<<dim3(8192), dim3(256), 0, stream>>>(x, xHi);
    xwi_gemm_mfma<<<dim3(8192), dim3(256), 0, stream>>>(xHi, WiHi, bb, G2);

    void* args[] = {(void*)&G2, (void*)&Wh, (void*)&h0, (void*)&c0, (void*)&out,
                    (void*)&hp0, (void*)&hp1, (void*)&flags};
    hipLaunchCooperativeKernel(reinterpret_cast<void*>(&lstm_scan_mfma),
                               dim3(256), dim3(256), args, 0, stream);
}

// Round 17
// 2027.617 us; speedup vs baseline: 2.7595x; 1.0876x over previous
//
#include <hip/hip_runtime.h>
#include <hip/hip_bf16.h>

// T=512, B=64, D=1024, H=1024, 4H=4096
// Pass 0a: pack Wi -> bf16 hi, MFMA B-fragment slab order (8MB)
// Pass 0b: pack x  -> bf16 hi, MFMA A-fragment slab order (64MB)
// Pass 1 : G2 = x @ Wi + b, single bf16 MFMA pass, both operands gl_lds.
// Pass 2 : cooperative scan (round-14/15/16 core). ROUND-17: the 256-WG
//          global barrier is split into 4 INDEPENDENT 64-WG class barriers
//          (class = batch-quarter bh): WG (jg,bh) only reads h produced by
//          class bh. h-pack layout partitioned per class (no cross-class
//          line sharing). Arithmetic identical.

typedef __attribute__((ext_vector_type(8))) short bf16x8;
typedef __attribute__((ext_vector_type(8))) unsigned short ushx8;
typedef __attribute__((ext_vector_type(4))) unsigned short ushx4;
typedef __attribute__((ext_vector_type(4))) float f32x4;
typedef __attribute__((ext_vector_type(2))) unsigned long long u64x2;

static __device__ __forceinline__ unsigned short f2bf(float x) {
    __hip_bfloat16 h = __float2bfloat16(x);
    return __builtin_bit_cast(unsigned short, h);
}
static __device__ __forceinline__ float bf2f(unsigned short u) {
    __hip_bfloat16 h = __builtin_bit_cast(__hip_bfloat16, u);
    return __bfloat162float(h);
}

// coherent (agent-scope, L2-bypassing) 16B load as 2 x u64 relaxed atomics
static __device__ __forceinline__ bf16x8 ld_h16(const unsigned long long* p) {
    unsigned long long a = __hip_atomic_load(p,     __ATOMIC_RELAXED, __HIP_MEMORY_SCOPE_AGENT);
    unsigned long long b = __hip_atomic_load(p + 1, __ATOMIC_RELAXED, __HIP_MEMORY_SCOPE_AGENT);
    u64x2 v; v.x = a; v.y = b;
    return __builtin_bit_cast(bf16x8, v);
}

static __device__ __forceinline__ void gl_lds16(const void* g, void* l) {
    __builtin_amdgcn_global_load_lds(
        (const __attribute__((address_space(1))) unsigned int*)g,
        (__attribute__((address_space(3))) unsigned int*)l, 16, 0, 0);
}

static __device__ __forceinline__ float sigm_fast(float x) {
    return 1.f / (1.f + __expf(-x));
}
static __device__ __forceinline__ float tanh_fast(float x) {
    float e = __expf(2.f * x);
    return 1.f - 2.f / (e + 1.f);
}

// ---------------------------------------------------------------------------
// Pass 0a: pack Wi[1024][4096] f32 -> WiHi bf16 (hi only), B-fragment slabs.
// ---------------------------------------------------------------------------
__global__ __launch_bounds__(256)
void wi_pack(const float* __restrict__ Wi, unsigned short* __restrict__ WiHi)
{
    const int bid = blockIdx.x;            // 1024 = tn(32) x kb(32)
    const int tn = bid >> 5, kb = bid & 31;
    const int t = threadIdx.x;
    const int c = t & 127, ko = t >> 7;
    const float* src = Wi + (size_t)(kb * 32 + ko * 16) * 4096 + tn * 128 + c;
    const size_t dbase = ((size_t)(tn * 32 + kb)) * 4096 + c * 8;
#pragma unroll
    for (int o = 0; o < 2; ++o) {
        ushx8 hv;
#pragma unroll
        for (int q = 0; q < 8; ++q)
            hv[q] = f2bf(src[(size_t)(o * 8 + q) * 4096]);
        int kq = ko * 2 + o;
        *(ushx8*)(WiHi + dbase + kq * 1024) = hv;
    }
}

// ---------------------------------------------------------------------------
// Pass 0b: pack x[32768][1024] f32 -> xHi bf16 (hi only), A-fragment slabs.
// ---------------------------------------------------------------------------
__global__ __launch_bounds__(256)
void x_pack(const float* __restrict__ x, unsigned short* __restrict__ xHi)
{
    const int bid = blockIdx.x;            // 8192 = bm(256) x kb(32)
    const int bm = bid >> 5, kb = bid & 31;
    const int t = threadIdx.x;
    const int row = t >> 1, kh = t & 1;
    const float* src = x + (size_t)(bm * 128 + row) * 1024 + kb * 32 + kh * 16;
    const size_t dbase = ((size_t)(bm * 32 + kb)) * 4096 + row * 8;

    float4 f0 = *(const float4*)(src + 0);
    float4 f1 = *(const float4*)(src + 4);
    float4 f2 = *(const float4*)(src + 8);
    float4 f3 = *(const float4*)(src + 12);
    float fs[16] = {f0.x, f0.y, f0.z, f0.w, f1.x, f1.y, f1.z, f1.w,
                    f2.x, f2.y, f2.z, f2.w, f3.x, f3.y, f3.z, f3.w};
#pragma unroll
    for (int o = 0; o < 2; ++o) {
        ushx8 hv;
#pragma unroll
        for (int q = 0; q < 8; ++q) hv[q] = f2bf(fs[o * 8 + q]);
        int kq = kh * 2 + o;
        *(ushx8*)(xHi + dbase + kq * 1024) = hv;
    }
}

// ---------------------------------------------------------------------------
// Pass 1: G2 = x @ Wi + bias; single bf16 pass, both operands global_load_lds.
// ---------------------------------------------------------------------------
__global__ __launch_bounds__(256)
void xwi_gemm_mfma(const unsigned short* __restrict__ xHi,
                   const unsigned short* __restrict__ WiHi,
                   const float* __restrict__ bias,
                   unsigned short* __restrict__ G2)
{
    __shared__ __align__(16) unsigned short AHi[4096];
    __shared__ __align__(16) unsigned short BHi[4096];
    const int bid = blockIdx.x;
    const int bm = bid >> 5, bn = bid & 31;
    const int m0 = bm << 7, n0 = bn << 7;
    const int t = threadIdx.x;
    const int w = t >> 6, l = t & 63, lq = l >> 4, lc = l & 15;
    const int wm = w >> 1, wn = w & 1;

    f32x4 acc[4][4] = {};
    const unsigned short* aSl = xHi + (size_t)(bm * 32) * 4096;
    const unsigned short* bSl = WiHi + (size_t)(bn * 32) * 4096;

    for (int kb = 0; kb < 32; ++kb) {
        {
            const unsigned short* sA = aSl + (size_t)kb * 4096;
            const unsigned short* sB = bSl + (size_t)kb * 4096;
            gl_lds16(sA + (size_t)(w * 128 + l) * 8,      &AHi[(w * 128) * 8]);
            gl_lds16(sA + (size_t)(w * 128 + 64 + l) * 8, &AHi[(w * 128 + 64) * 8]);
            gl_lds16(sB + (size_t)(w * 128 + l) * 8,      &BHi[(w * 128) * 8]);
            gl_lds16(sB + (size_t)(w * 128 + 64 + l) * 8, &BHi[(w * 128 + 64) * 8]);
        }
        __syncthreads();

        bf16x8 xh[4], wh_[4];
#pragma unroll
        for (int a = 0; a < 4; ++a) {
            int off = lq * 1024 + (wm * 64 + a * 16 + lc) * 8;
            xh[a] = *(const bf16x8*)&AHi[off];
        }
#pragma unroll
        for (int b = 0; b < 4; ++b) {
            int off = lq * 1024 + (wn * 64 + b * 16 + lc) * 8;
            wh_[b] = *(const bf16x8*)&BHi[off];
        }
#pragma unroll
        for (int a = 0; a < 4; ++a)
#pragma unroll
            for (int b = 0; b < 4; ++b)
                acc[a][b] = __builtin_amdgcn_mfma_f32_16x16x32_bf16(wh_[b], xh[a], acc[a][b], 0, 0, 0);
        __syncthreads();
    }

    float bv[4][4];
#pragma unroll
    for (int b = 0; b < 4; ++b)
#pragma unroll
        for (int r = 0; r < 4; ++r)
            bv[b][r] = bias[n0 + wn * 64 + b * 16 + lq * 4 + r];
#pragma unroll
    for (int a = 0; a < 4; ++a) {
        int m = m0 + wm * 64 + a * 16 + lc;
        int step = m >> 6, b_abs = m & 63;
        int bh_ = b_abs >> 4, b_l = b_abs & 15;
#pragma unroll
        for (int b = 0; b < 4; ++b) {
            int j_abs = n0 + wn * 64 + b * 16 + lq * 4;
            int gate = j_abs >> 10;
            int hid  = j_abs & 1023;
            int jg_t = hid >> 4, u0 = hid & 15;   // u0 in {0,4,8,12}
            ushx4 sv;
#pragma unroll
            for (int r = 0; r < 4; ++r) sv[r] = f2bf(acc[a][b][r] + bv[b][r]);
            size_t addr = (((size_t)(step * 64 + jg_t) * 4 + bh_) * 1024)
                          + gate * 256 + b_l * 16 + u0;
            *(ushx4*)(G2 + addr) = sv;
        }
    }
}

// ---------------------------------------------------------------------------
// Pass 2: cooperative MFMA scan. 256 WGs x 256 threads (4 waves), 1 WG/CU.
// WG (jg = wgid>>2, bh = wgid&3). ROUND-17: per-class (bh) barrier over 64
// WGs; h-pack partitioned per class: hp[bh][frag(128)][row(16)] fragments
// of 8 bf16 -> p32 = ((bh*128 + f)*16 + r)*4 + pair.
// ---------------------------------------------------------------------------
__global__ __launch_bounds__(256, 1)
void lstm_scan_mfma(const unsigned short* __restrict__ G2,
                    const float* __restrict__ Wh,
                    const float* __restrict__ h0, const float* __restrict__ c0,
                    float* __restrict__ out,
                    unsigned int* __restrict__ hp0,
                    unsigned int* __restrict__ hp1,
                    unsigned int* __restrict__ flags)
{
    __shared__ __align__(16) unsigned short WhHiS[65536];  // 128 KB, [gate][frag]
    __shared__ float zS[4 * 4 * 16 * 18];                  // 18.4 KB

    const int t    = threadIdx.x;
    const int wgid = blockIdx.x;         // 0..255
    const int jg   = wgid >> 2;          // 0..63
    const int bh   = wgid & 3;           // 0..3  (batch-quarter class)
    const int kh = t >> 6, l = t & 63, lq = l >> 4, lc = l & 15;

    // Wh slice -> LDS (once): 64 z-cols (cc = gate*16+u), hi only, B-frag order
    for (int idx = t; idx < 65536; idx += 256) {
        int k = idx >> 6, cc = idx & 63;
        int gate = cc >> 4, u = cc & 15;
        int gcol = gate * 1024 + jg * 16 + u;
        float wv = Wh[(size_t)k * 4096 + gcol];
        int pos = gate * 16384 + (((k >> 5) * 64) + (((k >> 3) & 3) * 16 + u)) * 8 + (k & 7);
        WhHiS[pos] = f2bf(wv);
    }

    // init hp0 from h0 (bf16 hi only, sc1 -> IF$): 128 pairs per WG,
    // class-partitioned layout.
    if (t < 128) {
        int idx = wgid * 128 + t;
        int b = idx >> 9, k = (idx & 511) * 2;
        unsigned short h0s = f2bf(h0[b * 1024 + k]);
        unsigned short h1s = f2bf(h0[b * 1024 + k + 1]);
        int p32 = (((b >> 4) * 128 + (k >> 3)) * 16 + (b & 15)) * 4 + ((k & 7) >> 1);
        __hip_atomic_store(hp0 + p32, (unsigned int)h0s | ((unsigned int)h1s << 16),
                           __ATOMIC_RELAXED, __HIP_MEMORY_SCOPE_AGENT);
    }

    const int b_l = t >> 4, u_el = t & 15;
    const int b_el = bh * 16 + b_l;
    const int j = jg * 16 + u_el;
    float c_state = c0[b_el * 1024 + j];

    // initial barrier: per-class (64 WGs). Arrive: flag (bh*64+jg).
    // Poll: wave 0 polls one class flag each.
    {
        asm volatile("s_waitcnt vmcnt(0)" ::: "memory");
        __syncthreads();
        if (t == 0)
            __hip_atomic_store(&flags[(bh * 64 + jg) * 32], 1u, __ATOMIC_RELAXED,
                               __HIP_MEMORY_SCOPE_AGENT);
        if (t < 64)
            while (__hip_atomic_load(&flags[(bh * 64 + t) * 32], __ATOMIC_RELAXED,
                                     __HIP_MEMORY_SCOPE_AGENT) < 1u) {}
        __syncthreads();
        asm volatile("" ::: "memory");
    }

    for (int step = 0; step < 512; ++step) {
        const unsigned long long* hH =
            (const unsigned long long*)((step & 1) ? hp1 : hp0);
        unsigned int* nH = (step & 1) ? hp0 : hp1;

        // G2 prefetch: contiguous 2KB/WG panel, 4 x 2B per thread (dense)
        size_t pb = (((size_t)(step * 64 + jg) * 4 + bh) * 1024) + t;
        unsigned short gvi = G2[pb];
        unsigned short gvf = G2[pb + 256];
        unsigned short gvg = G2[pb + 512];
        unsigned short gvo = G2[pb + 768];

        // K-quarter loop: 8 kb, distinct (rows x K-quarter) per wave.
        // Class-partitioned hp: frag f = kb*4+lq, row lc.
        bf16x8 ah[8];
#pragma unroll
        for (int i = 0; i < 8; ++i) {
            int kb = kh * 8 + i;
            int a64 = ((bh * 128 + kb * 4 + lq) * 16 + lc) * 2;
            ah[i] = ld_h16(hH + a64);
        }

        f32x4 acc[4] = {};
#pragma unroll
        for (int i = 0; i < 8; ++i) {
            int kb = kh * 8 + i;
            int b0 = (kb * 64 + l) * 8;
#pragma unroll
            for (int g = 0; g < 4; ++g) {
                bf16x8 bf = *(const bf16x8*)&WhHiS[g * 16384 + b0];
                acc[g] = __builtin_amdgcn_mfma_f32_16x16x32_bf16(ah[i], bf, acc[g], 0, 0, 0);
            }
        }

        // split-K partial -> zS[kh][g][row][col] (pad 18: <=2-way banks)
#pragma unroll
        for (int g = 0; g < 4; ++g)
#pragma unroll
            for (int r = 0; r < 4; ++r)
                zS[((kh * 4 + g) * 16 + lq * 4 + r) * 18 + lc] = acc[g][r];
        __syncthreads();

        // elementwise: thread owns (b_el, j); sum the 4 K-quarters per gate
        float zi = bf2f(gvi), zf = bf2f(gvf), zg = bf2f(gvg), zo = bf2f(gvo);
#pragma unroll
        for (int q = 0; q < 4; ++q) {
            const float* zq = zS + (q * 4 * 16) * 18;
            zi += zq[(0 * 16 + b_l) * 18 + u_el];
            zf += zq[(1 * 16 + b_l) * 18 + u_el];
            zg += zq[(2 * 16 + b_l) * 18 + u_el];
            zo += zq[(3 * 16 + b_l) * 18 + u_el];
        }

        float ig = sigm_fast(zi);
        float fg = sigm_fast(zf);
        float gg = tanh_fast(zg);
        float og = sigm_fast(zo);

        c_state = fg * c_state + ig * gg;
        float nh = og * tanh_fast(c_state);

        if (step == 511) {
            out[(size_t)step * 65536 + b_el * 1024 + j] = nh;
            break;                      // no publish/barrier needed
        }

        // publish h (bf16 hi only, sc1 -> IF$, class-partitioned layout)
        unsigned int hiw = f2bf(nh);
        unsigned int hi_o = (unsigned int)__shfl_xor((int)hiw, 1);
        if ((t & 1) == 0) {
            int p32 = ((bh * 128 + (j >> 3)) * 16 + b_l) * 4 + ((j & 7) >> 1);
            __hip_atomic_store(nH + p32, (hiw & 0xffffu) | (hi_o << 16),
                               __ATOMIC_RELAXED, __HIP_MEMORY_SCOPE_AGENT);
        }

        // per-class barrier: arrive (publishes drained), deferred out store,
        // wave-0 poll over the 64 class flags.
        asm volatile("s_waitcnt vmcnt(0)" ::: "memory");
        __syncthreads();
        unsigned int target = (unsigned int)(step + 2);
        if (t == 0)
            __hip_atomic_store(&flags[(bh * 64 + jg) * 32], target, __ATOMIC_RELAXED,
                               __HIP_MEMORY_SCOPE_AGENT);
        out[(size_t)step * 65536 + b_el * 1024 + j] = nh;   // drains next step
        if (t < 64)
            while (__hip_atomic_load(&flags[(bh * 64 + t) * 32], __ATOMIC_RELAXED,
                                     __HIP_MEMORY_SCOPE_AGENT) < target) {}
        __syncthreads();
        asm volatile("" ::: "memory");
    }
}

// ---------------------------------------------------------------------------
extern "C" void kernel_launch(void* const* d_in, const int* in_sizes, int n_in,
                              void* d_out, int out_size, void* d_ws, size_t ws_size,
                              hipStream_t stream)
{
    const float* x  = (const float*)d_in[0];
    const float* h0 = (const float*)d_in[1];
    const float* c0 = (const float*)d_in[2];
    const float* Wi = (const float*)d_in[3];
    const float* Wh = (const float*)d_in[4];
    const float* bb = (const float*)d_in[5];
    float* out = (float*)d_out;

    // ws layout: hp0/hp1 (128KB each) | flags 32KB | WiHi 8MB | xHi 64MB | G2 268MB
    unsigned int* hp0 = (unsigned int*)d_ws;
    unsigned int* hp1 = hp0 + 32768;
    unsigned int* flags = hp1 + 32768;          // 256 * 32 u32 = 32KB
    unsigned short* WiHi = (unsigned short*)(flags + 8192);
    unsigned short* xHi = WiHi + 4194304;       // 64MB
    unsigned short* G2 = xHi + 33554432;

    hipMemsetAsync(flags, 0, 8192 * sizeof(unsigned int), stream);
    wi_pack<<<dim3(1024), dim3(256), 0, stream>>>(Wi, WiHi);
    x_pack<<<dim3(8192), dim3(256), 0, stream>>>(x, xHi);
    xwi_gemm_mfma<<<dim3(8192), dim3(256), 0, stream>>>(xHi, WiHi, bb, G2);

    void* args[] = {(void*)&G2, (void*)&Wh, (void*)&h0, (void*)&c0, (void*)&out,
                    (void*)&hp0, (void*)&hp1, (void*)&flags};
    hipLaunchCooperativeKernel(reinterpret_cast<void*>(&lstm_scan_mfma),
                               dim3(256), dim3(256), args, 0, stream);
}